// Round 1
// baseline (4221.610 us; speedup 1.0000x reference)
//
#include <hip/hip_runtime.h>

#define Bn  16
#define Sn  2048
#define Hn  768
#define HHn 384

static constexpr float SCALE = 0.051031036307982884f; // 1/sqrt(384)

// ---------------------------------------------------------------------------
// Kernel 1: fused projection GEMM.  Y = X @ W + bias for W in {Wq, Wk, W1}.
// M=32768, K=768, N=384.  128x128 tile, BK=16, 256 threads, 8x8 micro-tile.
// ---------------------------------------------------------------------------
__global__ __launch_bounds__(256) void proj_gemm(
    const float* __restrict__ X,
    const float* __restrict__ Wq, const float* __restrict__ bq,
    const float* __restrict__ Wk, const float* __restrict__ bk,
    const float* __restrict__ W1, const float* __restrict__ b1,
    float* __restrict__ Qo, float* __restrict__ Ko, float* __restrict__ Uo)
{
    const float* W; const float* bias; float* Out;
    if (blockIdx.z == 0)      { W = Wq; bias = bq; Out = Qo; }
    else if (blockIdx.z == 1) { W = Wk; bias = bk; Out = Ko; }
    else                      { W = W1; bias = b1; Out = Uo; }

    const int m0  = blockIdx.x * 128;
    const int n0  = blockIdx.y * 128;
    const int tid = threadIdx.x;
    const int im  = tid >> 4;   // 0..15 -> rows im*8..+7
    const int jn  = tid & 15;   // 0..15 -> cols jn*8..+7

    __shared__ __align__(16) float sA[16][132];  // [k][m] (transposed)
    __shared__ __align__(16) float sB[16][132];  // [k][n]

    float acc[8][8];
#pragma unroll
    for (int i = 0; i < 8; ++i)
#pragma unroll
        for (int j = 0; j < 8; ++j) acc[i][j] = 0.f;

    for (int k0 = 0; k0 < Hn; k0 += 16) {
        __syncthreads();
#pragma unroll
        for (int it = 0; it < 2; ++it) {
            int f = tid + 256 * it;                  // 0..511 (128 rows x 4 f4)
            int row = f >> 2, k4 = (f & 3) * 4;
            float4 v = *reinterpret_cast<const float4*>(
                &X[(size_t)(m0 + row) * Hn + k0 + k4]);
            sA[k4 + 0][row] = v.x; sA[k4 + 1][row] = v.y;
            sA[k4 + 2][row] = v.z; sA[k4 + 3][row] = v.w;
        }
#pragma unroll
        for (int it = 0; it < 2; ++it) {
            int f = tid + 256 * it;                  // 0..511 (16 k x 32 f4)
            int kk = f >> 5, n4 = (f & 31) * 4;
            *reinterpret_cast<float4*>(&sB[kk][n4]) =
                *reinterpret_cast<const float4*>(&W[(size_t)(k0 + kk) * HHn + n0 + n4]);
        }
        __syncthreads();
#pragma unroll
        for (int kk = 0; kk < 16; ++kk) {
            float a[8], bb[8];
            *reinterpret_cast<float4*>(&a[0]) = *reinterpret_cast<const float4*>(&sA[kk][im * 8]);
            *reinterpret_cast<float4*>(&a[4]) = *reinterpret_cast<const float4*>(&sA[kk][im * 8 + 4]);
            *reinterpret_cast<float4*>(&bb[0]) = *reinterpret_cast<const float4*>(&sB[kk][jn * 8]);
            *reinterpret_cast<float4*>(&bb[4]) = *reinterpret_cast<const float4*>(&sB[kk][jn * 8 + 4]);
#pragma unroll
            for (int i = 0; i < 8; ++i)
#pragma unroll
                for (int j = 0; j < 8; ++j) acc[i][j] += a[i] * bb[j];
        }
    }
#pragma unroll
    for (int i = 0; i < 8; ++i) {
        size_t m = (size_t)m0 + im * 8 + i;
#pragma unroll
        for (int j = 0; j < 8; j += 4) {
            int n = n0 + jn * 8 + j;
            float4 v;
            v.x = acc[i][j + 0] + bias[n + 0];
            v.y = acc[i][j + 1] + bias[n + 1];
            v.z = acc[i][j + 2] + bias[n + 2];
            v.w = acc[i][j + 3] + bias[n + 3];
            *reinterpret_cast<float4*>(&Out[m * HHn + n]) = v;
        }
    }
}

// ---------------------------------------------------------------------------
// Kernel 2: fused attention.  Hpre = softmax(QK^T/sqrt(384), key-masked) @ U + b1
// Per block: one batch b, 64 queries.  Tk=64 keys/iter.  256 threads.
// No max-subtraction (logits ~N(0,0.3); masked keys exp(-1e4)=0).
// NOTE: Hp aliases Qg (each block reads only its own q-rows) -> no __restrict__.
// ---------------------------------------------------------------------------
__global__ __launch_bounds__(256) void attn_kernel(
    const float* Qg, const float* __restrict__ Kg, const float* __restrict__ Ug,
    const float* __restrict__ b1, const int* __restrict__ am, float* Hp)
{
    __shared__ __align__(16) float sQK[8704];  // sQ [64][68] @0, sK @4352; sU [16][388] aliases @0
    __shared__ __align__(16) float sP[64 * 68];
    __shared__ float sDen[64];

    const int tid = threadIdx.x;
    const int b  = blockIdx.y;
    const int q0 = blockIdx.x * 64;
    const float* Qb = Qg + ((size_t)b * Sn + q0) * HHn;
    const float* Kb = Kg + (size_t)b * Sn * HHn;
    const float* Ub = Ug + (size_t)b * Sn * HHn;
    const int*  amb = am + b * Sn;

    const int ig = tid >> 4;  // score rows: ig + 16r
    const int jg = tid & 15;  // score cols: jg + 16c   (stride-16 -> conflict-free)
    const int rg = tid >> 5;  // PV rows: rg*8 + r
    const int dg = tid & 31;  // PV dims: dg*12 + dd

    float o[8][12];
#pragma unroll
    for (int r = 0; r < 8; ++r)
#pragma unroll
        for (int d = 0; d < 12; ++d) o[r][d] = 0.f;
    float den = 0.f;  // only tid<64 meaningful (owns row=tid)

    for (int kt = 0; kt < 32; ++kt) {
        const int t0 = kt * 64;
        float sc[4][4];
#pragma unroll
        for (int r = 0; r < 4; ++r)
#pragma unroll
            for (int c = 0; c < 4; ++c) sc[r][c] = 0.f;

        for (int dc = 0; dc < 6; ++dc) {          // d-chunks of 64
            __syncthreads();
#pragma unroll
            for (int it = 0; it < 4; ++it) {
                int f = tid + 256 * it;           // 0..1023 (64 rows x 16 f4)
                int row = f >> 4, k4 = (f & 15) * 4;
                *reinterpret_cast<float4*>(&sQK[row * 68 + k4]) =
                    *reinterpret_cast<const float4*>(&Qb[(size_t)row * HHn + dc * 64 + k4]);
                *reinterpret_cast<float4*>(&sQK[4352 + row * 68 + k4]) =
                    *reinterpret_cast<const float4*>(&Kb[(size_t)(t0 + row) * HHn + dc * 64 + k4]);
            }
            __syncthreads();
#pragma unroll
            for (int d4 = 0; d4 < 16; ++d4) {
                float4 qa[4], kb[4];
#pragma unroll
                for (int r = 0; r < 4; ++r)
                    qa[r] = *reinterpret_cast<const float4*>(&sQK[(ig + 16 * r) * 68 + d4 * 4]);
#pragma unroll
                for (int c = 0; c < 4; ++c)
                    kb[c] = *reinterpret_cast<const float4*>(&sQK[4352 + (jg + 16 * c) * 68 + d4 * 4]);
#pragma unroll
                for (int r = 0; r < 4; ++r)
#pragma unroll
                    for (int c = 0; c < 4; ++c)
                        sc[r][c] += qa[r].x * kb[c].x + qa[r].y * kb[c].y +
                                    qa[r].z * kb[c].z + qa[r].w * kb[c].w;
            }
        }
        // exp -> P (key mask applied post-scale, like reference)
#pragma unroll
        for (int c = 0; c < 4; ++c) {
            int col = jg + 16 * c;
            bool msk = (amb[t0 + col] == 0);
#pragma unroll
            for (int r = 0; r < 4; ++r) {
                float v = msk ? -10000.0f : sc[r][c] * SCALE;
                sP[(ig + 16 * r) * 68 + col] = __expf(v);
            }
        }
        __syncthreads();
        if (tid < 64) {  // denominator partial for row=tid
            float s = 0.f;
#pragma unroll
            for (int j4 = 0; j4 < 16; ++j4) {
                float4 p = *reinterpret_cast<const float4*>(&sP[tid * 68 + j4 * 4]);
                s += p.x + p.y + p.z + p.w;
            }
            den += s;
        }
        // PV: U streamed in sub-tiles of 16 keys (full 384 dims each)
        for (int jt = 0; jt < 4; ++jt) {
            __syncthreads();
#pragma unroll
            for (int it = 0; it < 6; ++it) {
                int f = tid + 256 * it;           // 0..1535 (16 rows x 96 f4)
                int j = f / 96, d4 = (f % 96) * 4;
                *reinterpret_cast<float4*>(&sQK[j * 388 + d4]) =
                    *reinterpret_cast<const float4*>(&Ub[(size_t)(t0 + jt * 16 + j) * HHn + d4]);
            }
            __syncthreads();
#pragma unroll
            for (int jj = 0; jj < 16; jj += 4) {
                float4 pr[8];
#pragma unroll
                for (int r = 0; r < 8; ++r)
                    pr[r] = *reinterpret_cast<const float4*>(&sP[(rg * 8 + r) * 68 + jt * 16 + jj]);
#pragma unroll
                for (int d4i = 0; d4i < 3; ++d4i) {
                    float4 u0 = *reinterpret_cast<const float4*>(&sQK[(jj + 0) * 388 + dg * 12 + d4i * 4]);
                    float4 u1 = *reinterpret_cast<const float4*>(&sQK[(jj + 1) * 388 + dg * 12 + d4i * 4]);
                    float4 u2 = *reinterpret_cast<const float4*>(&sQK[(jj + 2) * 388 + dg * 12 + d4i * 4]);
                    float4 u3 = *reinterpret_cast<const float4*>(&sQK[(jj + 3) * 388 + dg * 12 + d4i * 4]);
#pragma unroll
                    for (int r = 0; r < 8; ++r) {
                        o[r][d4i * 4 + 0] += pr[r].x * u0.x + pr[r].y * u1.x + pr[r].z * u2.x + pr[r].w * u3.x;
                        o[r][d4i * 4 + 1] += pr[r].x * u0.y + pr[r].y * u1.y + pr[r].z * u2.y + pr[r].w * u3.y;
                        o[r][d4i * 4 + 2] += pr[r].x * u0.z + pr[r].y * u1.z + pr[r].z * u2.z + pr[r].w * u3.z;
                        o[r][d4i * 4 + 3] += pr[r].x * u0.w + pr[r].y * u1.w + pr[r].z * u2.w + pr[r].w * u3.w;
                    }
                }
            }
        }
    }
    __syncthreads();
    if (tid < 64) sDen[tid] = den;
    __syncthreads();
#pragma unroll
    for (int r = 0; r < 8; ++r) {
        int row = rg * 8 + r;
        float inv = 1.0f / sDen[row];
#pragma unroll
        for (int d4i = 0; d4i < 3; ++d4i) {
            int d = dg * 12 + d4i * 4;
            float4 v;
            v.x = o[r][d4i * 4 + 0] * inv + b1[d + 0];
            v.y = o[r][d4i * 4 + 1] * inv + b1[d + 1];
            v.z = o[r][d4i * 4 + 2] * inv + b1[d + 2];
            v.w = o[r][d4i * 4 + 3] * inv + b1[d + 3];
            *reinterpret_cast<float4*>(&Hp[((size_t)b * Sn + q0 + row) * HHn + d]) = v;
        }
    }
}

// ---------------------------------------------------------------------------
// Kernel 3: LN(g1,be1) + relu + dot(W2) + b2 + mask  -> token_scores
// One wave per row (384 dims = 6/lane), 4 rows/block.
// ---------------------------------------------------------------------------
__global__ __launch_bounds__(256) void ln_score_kernel(
    const float* __restrict__ Hp, const float* __restrict__ g1, const float* __restrict__ be1,
    const float* __restrict__ W2, const float* __restrict__ b2,
    const int* __restrict__ am, float* __restrict__ scores)
{
    const int row  = blockIdx.x * 4 + (threadIdx.x >> 6);
    const int lane = threadIdx.x & 63;
    const float* x = Hp + (size_t)row * HHn;
    float v[6];
#pragma unroll
    for (int j = 0; j < 6; ++j) v[j] = x[lane + 64 * j];
    float s = 0.f;
#pragma unroll
    for (int j = 0; j < 6; ++j) s += v[j];
#pragma unroll
    for (int off = 32; off > 0; off >>= 1) s += __shfl_xor(s, off, 64);
    const float mean = s * (1.0f / 384.0f);
    float q = 0.f;
#pragma unroll
    for (int j = 0; j < 6; ++j) { float d = v[j] - mean; q += d * d; }
#pragma unroll
    for (int off = 32; off > 0; off >>= 1) q += __shfl_xor(q, off, 64);
    const float rstd = rsqrtf(q * (1.0f / 384.0f) + 1e-5f);
    float part = 0.f;
#pragma unroll
    for (int j = 0; j < 6; ++j) {
        int d = lane + 64 * j;
        float h = (v[j] - mean) * rstd * g1[d] + be1[d];
        h = fmaxf(h, 0.f);
        part += h * W2[d];
    }
#pragma unroll
    for (int off = 32; off > 0; off >>= 1) part += __shfl_xor(part, off, 64);
    if (lane == 0) {
        float scv = part + b2[0];
        if (am[row] == 0) scv = -10000.0f;
        scores[row] = scv;
    }
}

// ---------------------------------------------------------------------------
// Kernel 4: span search (torch flat-argmax semantics, l-major, first max) + pooling.
// One block per batch.
// ---------------------------------------------------------------------------
__global__ __launch_bounds__(256) void span_pool_kernel(
    const float* __restrict__ scores, const int* __restrict__ am,
    const float* __restrict__ X, float* __restrict__ pooled)
{
    __shared__ float cum[Sn + 1];
    __shared__ float psum[257];
    __shared__ float bval[256];
    __shared__ int   bidx[256];
    __shared__ int   sred[256];
    __shared__ int   sInfo[2];

    const int b = blockIdx.x, tid = threadIdx.x;

    int vl = 0;
    for (int i = tid; i < Sn; i += 256) vl += am[b * Sn + i];
    sred[tid] = vl;
    __syncthreads();
    if (tid == 0) {
        int t = 0;
        for (int i = 0; i < 256; ++i) t += sred[i];
        sInfo[0] = t;
    }
    __syncthreads();
    const int valid_len = sInfo[0];

    // blocked prefix sum of scores -> cum[0..2048]
    float loc[8]; float tot = 0.f;
#pragma unroll
    for (int k2 = 0; k2 < 8; ++k2) { loc[k2] = scores[b * Sn + tid * 8 + k2]; tot += loc[k2]; }
    psum[tid + 1] = tot;
    __syncthreads();
    if (tid == 0) {
        psum[0] = 0.f;
        float r = 0.f;
        for (int i = 1; i <= 256; ++i) { float t = psum[i]; psum[i] = r + t; r += t; }
        // psum[i] now = inclusive prefix of thread totals 0..i-1 ... fix to exclusive below
    }
    __syncthreads();
    {
        float r = (tid == 0) ? 0.f : psum[tid];   // exclusive base for this thread
        if (tid == 0) cum[0] = 0.f;
#pragma unroll
        for (int k2 = 0; k2 < 8; ++k2) { r += loc[k2]; cum[tid * 8 + k2 + 1] = r; }
    }
    __syncthreads();

    // candidate scan: flat = l*2048 + start, l-major, first-max tie rule
    float bv = -3.0e30f; int bi = 0x7fffffff;
    for (int flat = tid; flat < 18 * Sn; flat += 256) {
        int l  = flat >> 11;
        int st = flat & (Sn - 1);
        int L  = 3 + l;
        int end = st + L;
        float val;
        if (end <= valid_len) {
            int ec = end < Sn ? end : Sn;
            val = (cum[ec] - cum[st]) / (float)L + (0.01f * (float)L) / 20.0f;
        } else val = -1.0e30f;
        if (val > bv) { bv = val; bi = flat; }
    }
    bval[tid] = bv; bidx[tid] = bi;
    __syncthreads();
    if (tid == 0) {
        float best = bval[0]; int besti = bidx[0];
        for (int i = 1; i < 256; ++i) {
            if (bval[i] > best || (bval[i] == best && bidx[i] < besti)) {
                best = bval[i]; besti = bidx[i];
            }
        }
        int st, len;
        if (valid_len <= 3) { st = 0; len = valid_len; }
        else { int l = besti >> 11; st = besti & (Sn - 1); len = 3 + l; }
        sInfo[0] = st; sInfo[1] = len;
    }
    __syncthreads();
    const int st = sInfo[0], len = sInfo[1];
    for (int d = tid; d < Hn; d += 256) {
        float s2 = 0.f;
        for (int i = 0; i < len; ++i) s2 += X[((size_t)b * Sn + st + i) * Hn + d];
        pooled[b * Hn + d] = s2 / ((float)len + 1e-6f);
    }
}

// ---------------------------------------------------------------------------
// Kernel 5: head.  pooled -> LN(relu) -> Wc2 -> sym interaction -> sigmoid ->
//           concat with cls_emb -> Wcls -> logits.  One block per batch, 384 thr.
// ---------------------------------------------------------------------------
__global__ __launch_bounds__(384) void head_kernel(
    const float* __restrict__ pooled,
    const float* __restrict__ Wc1, const float* __restrict__ bc1,
    const float* __restrict__ g2, const float* __restrict__ be2,
    const float* __restrict__ Wc2, const float* __restrict__ bc2,
    const float* __restrict__ Mint,
    const float* __restrict__ Wcls, const float* __restrict__ bcls,
    const float* __restrict__ X, float* __restrict__ out)
{
    __shared__ float sp[768];
    __shared__ float sh[384];
    __shared__ float scs[64];
    __shared__ float scp[64];
    __shared__ float red[6];
    __shared__ float stat;

    const int b = blockIdx.x, tid = threadIdx.x;
    sp[tid]       = pooled[b * Hn + tid];
    sp[tid + 384] = pooled[b * Hn + 384 + tid];
    __syncthreads();

    float z = bc1[tid];
    for (int k2 = 0; k2 < Hn; ++k2) z += sp[k2] * Wc1[(size_t)k2 * HHn + tid];

    float s = z;
#pragma unroll
    for (int off = 32; off > 0; off >>= 1) s += __shfl_xor(s, off, 64);
    if ((tid & 63) == 0) red[tid >> 6] = s;
    __syncthreads();
    if (tid == 0) stat = (red[0] + red[1] + red[2] + red[3] + red[4] + red[5]) * (1.0f / 384.0f);
    __syncthreads();
    const float mean = stat;
    float dv = z - mean;
    float qq = dv * dv;
#pragma unroll
    for (int off = 32; off > 0; off >>= 1) qq += __shfl_xor(qq, off, 64);
    if ((tid & 63) == 0) red[tid >> 6] = qq;
    __syncthreads();
    if (tid == 0) stat = (red[0] + red[1] + red[2] + red[3] + red[4] + red[5]) * (1.0f / 384.0f);
    __syncthreads();
    const float rstd = rsqrtf(stat + 1e-5f);
    float h = fmaxf(dv * rstd * g2[tid] + be2[tid], 0.f);
    sh[tid] = h;
    __syncthreads();
    if (tid < 64) {
        float c = bc2[tid];
        for (int k2 = 0; k2 < HHn; ++k2) c += sh[k2] * Wc2[k2 * 64 + tid];
        scs[tid] = c;
    }
    __syncthreads();
    if (tid < 64) {
        float a2 = scs[tid];
        for (int c2 = 0; c2 < 64; ++c2) {
            float m   = 0.5f * (Mint[c2 * 64 + tid] + Mint[tid * 64 + c2]);
            float sym = 1.0f / (1.0f + expf(-m));
            a2 += scs[c2] * sym;
        }
        scp[tid] = 1.0f / (1.0f + expf(-a2));
    }
    __syncthreads();
    if (tid < 4) {
        float lg = bcls[tid];
        for (int c2 = 0; c2 < 64; ++c2) lg += scp[c2] * Wcls[c2 * 4 + tid];
        const float* cls = X + (size_t)b * Sn * Hn;   // x[b, 0, :]
        for (int d2 = 0; d2 < Hn; ++d2) lg += cls[d2] * Wcls[(64 + d2) * 4 + tid];
        out[b * 4 + tid] = lg;
    }
}

// ---------------------------------------------------------------------------
extern "C" void kernel_launch(void* const* d_in, const int* in_sizes, int n_in,
                              void* d_out, int out_size, void* d_ws, size_t ws_size,
                              hipStream_t stream)
{
    const float* X    = (const float*)d_in[0];
    const int*   am   = (const int*)  d_in[1];
    const float* Wq   = (const float*)d_in[2];
    const float* bq   = (const float*)d_in[3];
    const float* Wk   = (const float*)d_in[4];
    const float* bk   = (const float*)d_in[5];
    const float* W1   = (const float*)d_in[6];
    const float* b1   = (const float*)d_in[7];
    const float* g1   = (const float*)d_in[8];
    const float* be1  = (const float*)d_in[9];
    const float* W2   = (const float*)d_in[10];
    const float* b2   = (const float*)d_in[11];
    const float* Wc1  = (const float*)d_in[12];
    const float* bc1  = (const float*)d_in[13];
    const float* g2   = (const float*)d_in[14];
    const float* be2  = (const float*)d_in[15];
    const float* Wc2  = (const float*)d_in[16];
    const float* bc2  = (const float*)d_in[17];
    const float* Mint = (const float*)d_in[18];
    const float* Wcls = (const float*)d_in[19];
    const float* bcls = (const float*)d_in[20];

    float* ws = (float*)d_ws;
    const size_t NT = (size_t)Bn * Sn * HHn;     // 12,582,912 floats
    float* Q      = ws;
    float* K      = ws + NT;
    float* U      = ws + 2 * NT;
    float* Hp     = Q;                            // alias: block-local rows only
    float* scores = ws + 3 * NT;
    float* pooled = scores + (size_t)Bn * Sn;
    // total ws use: 3*NT + 32768 + 12288 floats = 144.2 MiB

    proj_gemm<<<dim3(256, 3, 3), 256, 0, stream>>>(X, Wq, bq, Wk, bk, W1, b1, Q, K, U);
    attn_kernel<<<dim3(Sn / 64, Bn), 256, 0, stream>>>(Q, K, U, b1, am, Hp);
    ln_score_kernel<<<(Bn * Sn) / 4, 256, 0, stream>>>(Hp, g1, be1, W2, b2, am, scores);
    span_pool_kernel<<<Bn, 256, 0, stream>>>(scores, am, X, pooled);
    head_kernel<<<Bn, 384, 0, stream>>>(pooled, Wc1, bc1, g2, be2, Wc2, bc2,
                                        Mint, Wcls, bcls, X, (float*)d_out);
}

// Round 2
// 2424.098 us; speedup vs baseline: 1.7415x; 1.7415x over previous
//
#include <hip/hip_runtime.h>
#include <hip/hip_bf16.h>

#define Bn  16
#define Sn  2048
#define Hn  768
#define HHn 384

typedef unsigned short ushortT;
typedef __attribute__((ext_vector_type(8))) short short8;
typedef __attribute__((ext_vector_type(4))) float f32x4;

static constexpr float SCALE = 0.051031036307982884f; // 1/sqrt(384)
static constexpr float EPS_PATCH = 0.02f;             // ~40 sigma of bf16 path error

static __device__ __forceinline__ float bf2f(ushortT u) {
    return __uint_as_float(((unsigned int)u) << 16);
}
static __device__ __forceinline__ ushortT f2bf(float f) {
    __hip_bfloat16 h = __float2bfloat16(f);
    return *reinterpret_cast<ushortT*>(&h);
}

// ---------------------------------------------------------------------------
// Kernel 1: projection GEMM (fp32 compute, round-1 structure).
// Outputs: Qhi (bf16), Khi+Klo (bf16 hi/lo), Ut_hi+Ut_lo (bf16 hi/lo, TRANSPOSED
// [b][d][s] so attention PV B-fragments are contiguous).
// ---------------------------------------------------------------------------
__global__ __launch_bounds__(256) void proj_gemm(
    const float* __restrict__ X,
    const float* __restrict__ Wq, const float* __restrict__ bq,
    const float* __restrict__ Wk, const float* __restrict__ bk,
    const float* __restrict__ W1, const float* __restrict__ b1,
    ushortT* __restrict__ Qhi, ushortT* __restrict__ Khi, ushortT* __restrict__ Klo,
    ushortT* __restrict__ Uthi, ushortT* __restrict__ Utlo)
{
    const float* W; const float* bias;
    const int wsel = blockIdx.z;
    if (wsel == 0)      { W = Wq; bias = bq; }
    else if (wsel == 1) { W = Wk; bias = bk; }
    else                { W = W1; bias = b1; }

    const int m0  = blockIdx.x * 128;
    const int n0  = blockIdx.y * 128;
    const int tid = threadIdx.x;
    const int im  = tid >> 4;
    const int jn  = tid & 15;

    __shared__ __align__(16) float sA[16][132];
    __shared__ __align__(16) float sB[16][132];

    float acc[8][8];
#pragma unroll
    for (int i = 0; i < 8; ++i)
#pragma unroll
        for (int j = 0; j < 8; ++j) acc[i][j] = 0.f;

    for (int k0 = 0; k0 < Hn; k0 += 16) {
        __syncthreads();
#pragma unroll
        for (int it = 0; it < 2; ++it) {
            int f = tid + 256 * it;
            int row = f >> 2, k4 = (f & 3) * 4;
            float4 v = *reinterpret_cast<const float4*>(
                &X[(size_t)(m0 + row) * Hn + k0 + k4]);
            sA[k4 + 0][row] = v.x; sA[k4 + 1][row] = v.y;
            sA[k4 + 2][row] = v.z; sA[k4 + 3][row] = v.w;
        }
#pragma unroll
        for (int it = 0; it < 2; ++it) {
            int f = tid + 256 * it;
            int kk = f >> 5, n4 = (f & 31) * 4;
            *reinterpret_cast<float4*>(&sB[kk][n4]) =
                *reinterpret_cast<const float4*>(&W[(size_t)(k0 + kk) * HHn + n0 + n4]);
        }
        __syncthreads();
#pragma unroll
        for (int kk = 0; kk < 16; ++kk) {
            float a[8], bb[8];
            *reinterpret_cast<float4*>(&a[0])  = *reinterpret_cast<const float4*>(&sA[kk][im * 8]);
            *reinterpret_cast<float4*>(&a[4])  = *reinterpret_cast<const float4*>(&sA[kk][im * 8 + 4]);
            *reinterpret_cast<float4*>(&bb[0]) = *reinterpret_cast<const float4*>(&sB[kk][jn * 8]);
            *reinterpret_cast<float4*>(&bb[4]) = *reinterpret_cast<const float4*>(&sB[kk][jn * 8 + 4]);
#pragma unroll
            for (int i = 0; i < 8; ++i)
#pragma unroll
                for (int j = 0; j < 8; ++j) acc[i][j] += a[i] * bb[j];
        }
    }

    if (wsel == 2) {
        // U: write transposed hi/lo  Ut[b][n][s]
        const int bb = m0 / Sn;
        const int s0 = (m0 % Sn) + im * 8;
        const size_t ub = (size_t)bb * HHn * Sn;
#pragma unroll
        for (int j = 0; j < 8; ++j) {
            int n = n0 + jn * 8 + j;
            float bv = bias[n];
            short8 hv, lv;
#pragma unroll
            for (int i = 0; i < 8; ++i) {
                float v = acc[i][j] + bv;
                ushortT hb = f2bf(v);
                hv[i] = (short)hb;
                lv[i] = (short)f2bf(v - bf2f(hb));
            }
            *reinterpret_cast<short8*>(&Uthi[ub + (size_t)n * Sn + s0]) = hv;
            *reinterpret_cast<short8*>(&Utlo[ub + (size_t)n * Sn + s0]) = lv;
        }
    } else {
#pragma unroll
        for (int i = 0; i < 8; ++i) {
            size_t m = (size_t)m0 + im * 8 + i;
            int nb = n0 + jn * 8;
            short8 hv, lv;
#pragma unroll
            for (int j = 0; j < 8; ++j) {
                float v = acc[i][j] + bias[nb + j];
                ushortT hb = f2bf(v);
                hv[j] = (short)hb;
                lv[j] = (short)f2bf(v - bf2f(hb));
            }
            if (wsel == 0) {
                *reinterpret_cast<short8*>(&Qhi[m * HHn + nb]) = hv;
            } else {
                *reinterpret_cast<short8*>(&Khi[m * HHn + nb]) = hv;
                *reinterpret_cast<short8*>(&Klo[m * HHn + nb]) = lv;
            }
        }
    }
}

// ---------------------------------------------------------------------------
// Kernel 2: bf16 MFMA flash attention.  Hp = softmax(QK^T*SCALE, masked) @ U
// (U = X@W1+b1, so Hp = ctx@W1 + b1).  Block = 256 thr (4 waves), q-tile 64,
// key tiles of 64, 1 block/CU (127.7 KB LDS), register prefetch of K/U tiles.
// Verified fragment layouts: A[m=lane&15][k=quad*8+j]; C/D col=lane&15,
// row=quad*4+reg.  Hp aliases Qhi (exact row correspondence -> safe).
// ---------------------------------------------------------------------------
__global__ __launch_bounds__(256, 1) void attn_mfma(
    const ushortT* Qg, const ushortT* __restrict__ Kg, const ushortT* __restrict__ Utg,
    const int* __restrict__ am, ushortT* Hp)
{
    __shared__ __align__(16) unsigned char smem[127744];
    ushortT* sQ   = (ushortT*)smem;                  // [64][392] bf16
    ushortT* sKU  = (ushortT*)(smem + 50176);        // K:[64][392] / U:[384][88]
    ushortT* sP   = (ushortT*)(smem + 117760);       // [64][72] bf16
    float*   sDen = (float*)(smem + 126976);         // [64]
    float*   sDenP= (float*)(smem + 127232);         // [2][64]

    const int tid  = threadIdx.x;
    const int wid  = tid >> 6;
    const int lane = tid & 63;
    const int quad = lane >> 4;
    const int l15  = lane & 15;
    const int b    = blockIdx.y;
    const int q0   = blockIdx.x * 64;
    const size_t rowbase = (size_t)(b * Sn + q0);
    const size_t kbase   = (size_t)(b * Sn);
    const size_t ub      = (size_t)b * HHn * Sn;
    const int* amb = am + b * Sn;

    const int srow = tid >> 2;        // 0..63
    const int sseg = (tid & 3) * 12;  // + it -> 0..47

    // stage Q tile (bf16, padded stride 392 -> 2-way bank alias = free)
#pragma unroll
    for (int it = 0; it < 12; ++it) {
        uint4 v = *reinterpret_cast<const uint4*>(&Qg[(rowbase + srow) * HHn + (sseg + it) * 8]);
        *reinterpret_cast<uint4*>(&sQ[srow * 392 + (sseg + it) * 8]) = v;
    }
    if (tid < 64) sDen[tid] = 0.f;

    uint4 kreg[12], ureg[12];
#pragma unroll
    for (int it = 0; it < 12; ++it)
        kreg[it] = *reinterpret_cast<const uint4*>(&Kg[(kbase + srow) * HHn + (sseg + it) * 8]);

    const int rowoff = 32 * (wid >> 1);
    const int coloff = 32 * (wid & 1);

    f32x4 o[4][6];
#pragma unroll
    for (int rt = 0; rt < 4; ++rt)
#pragma unroll
        for (int dt = 0; dt < 6; ++dt) o[rt][dt] = (f32x4){0.f, 0.f, 0.f, 0.f};

    __syncthreads();

    for (int kt = 0; kt < 32; ++kt) {
        const int t0 = kt * 64;
        // K regs -> LDS
#pragma unroll
        for (int it = 0; it < 12; ++it)
            *reinterpret_cast<uint4*>(&sKU[srow * 392 + (sseg + it) * 8]) = kreg[it];
        __syncthreads();

        // prefetch U tile (transposed source: contiguous in keys)
#pragma unroll
        for (int it = 0; it < 12; ++it) {
            int g = it * 256 + tid;
            int dim = g >> 3, seg = g & 7;
            ureg[it] = *reinterpret_cast<const uint4*>(&Utg[ub + (size_t)dim * Sn + t0 + seg * 8]);
        }

        // QK^T: wave covers rows rowoff..+31, cols coloff..+31 (2x2 16-tiles)
        f32x4 sc[2][2];
#pragma unroll
        for (int rt = 0; rt < 2; ++rt)
#pragma unroll
            for (int ct = 0; ct < 2; ++ct) sc[rt][ct] = (f32x4){0.f, 0.f, 0.f, 0.f};
#pragma unroll
        for (int ks = 0; ks < 12; ++ks) {
            short8 a0 = *reinterpret_cast<const short8*>(&sQ[(rowoff      + l15) * 392 + ks * 32 + quad * 8]);
            short8 a1 = *reinterpret_cast<const short8*>(&sQ[(rowoff + 16 + l15) * 392 + ks * 32 + quad * 8]);
            short8 b0 = *reinterpret_cast<const short8*>(&sKU[(coloff      + l15) * 392 + ks * 32 + quad * 8]);
            short8 b1 = *reinterpret_cast<const short8*>(&sKU[(coloff + 16 + l15) * 392 + ks * 32 + quad * 8]);
            sc[0][0] = __builtin_amdgcn_mfma_f32_16x16x32_bf16(a0, b0, sc[0][0], 0, 0, 0);
            sc[0][1] = __builtin_amdgcn_mfma_f32_16x16x32_bf16(a0, b1, sc[0][1], 0, 0, 0);
            sc[1][0] = __builtin_amdgcn_mfma_f32_16x16x32_bf16(a1, b0, sc[1][0], 0, 0, 0);
            sc[1][1] = __builtin_amdgcn_mfma_f32_16x16x32_bf16(a1, b1, sc[1][1], 0, 0, 0);
        }

        // P = exp(s*SCALE) (masked -> 0), write bf16 P, row-sum partials
        float dp[2][4];
#pragma unroll
        for (int rt = 0; rt < 2; ++rt)
#pragma unroll
            for (int rg = 0; rg < 4; ++rg) dp[rt][rg] = 0.f;
#pragma unroll
        for (int ct = 0; ct < 2; ++ct) {
            int col = coloff + 16 * ct + l15;
            float mval = (amb[t0 + col] != 0) ? 1.f : 0.f;
#pragma unroll
            for (int rt = 0; rt < 2; ++rt)
#pragma unroll
                for (int rg = 0; rg < 4; ++rg) {
                    int row = rowoff + 16 * rt + quad * 4 + rg;
                    float p = __expf(sc[rt][ct][rg] * SCALE) * mval;
                    sP[row * 72 + col] = f2bf(p);
                    dp[rt][rg] += p;
                }
        }
#pragma unroll
        for (int off = 1; off < 16; off <<= 1)
#pragma unroll
            for (int rt = 0; rt < 2; ++rt)
#pragma unroll
                for (int rg = 0; rg < 4; ++rg)
                    dp[rt][rg] += __shfl_xor(dp[rt][rg], off, 16);
        if (l15 == 0) {
#pragma unroll
            for (int rt = 0; rt < 2; ++rt)
#pragma unroll
                for (int rg = 0; rg < 4; ++rg)
                    sDenP[(wid & 1) * 64 + rowoff + 16 * rt + quad * 4 + rg] = dp[rt][rg];
        }
        __syncthreads();
        if (tid < 64) sDen[tid] += sDenP[tid] + sDenP[64 + tid];

        // U regs -> LDS (overwrites K region; all QK reads done)
#pragma unroll
        for (int it = 0; it < 12; ++it) {
            int g = it * 256 + tid;
            int dim = g >> 3, seg = g & 7;
            *reinterpret_cast<uint4*>(&sKU[dim * 88 + seg * 8]) = ureg[it];
        }
        // prefetch next K tile
        if (kt < 31) {
#pragma unroll
            for (int it = 0; it < 12; ++it)
                kreg[it] = *reinterpret_cast<const uint4*>(
                    &Kg[(kbase + t0 + 64 + srow) * HHn + (sseg + it) * 8]);
        }
        __syncthreads();

        // PV: wave covers all 64 rows x dims 96*wid..+95 (4rt x 6dt tiles)
#pragma unroll
        for (int ks = 0; ks < 2; ++ks) {
            short8 pa[4];
#pragma unroll
            for (int rt = 0; rt < 4; ++rt)
                pa[rt] = *reinterpret_cast<const short8*>(&sP[(16 * rt + l15) * 72 + ks * 32 + quad * 8]);
#pragma unroll
            for (int dt = 0; dt < 6; ++dt) {
                short8 u = *reinterpret_cast<const short8*>(
                    &sKU[(96 * wid + 16 * dt + l15) * 88 + ks * 32 + quad * 8]);
#pragma unroll
                for (int rt = 0; rt < 4; ++rt)
                    o[rt][dt] = __builtin_amdgcn_mfma_f32_16x16x32_bf16(pa[rt], u, o[rt][dt], 0, 0, 0);
            }
        }
        __syncthreads();
    }

    // epilogue: Hp = O/den (U already contains +b1), bf16 store
#pragma unroll
    for (int rt = 0; rt < 4; ++rt)
#pragma unroll
        for (int rg = 0; rg < 4; ++rg) {
            int row = 16 * rt + quad * 4 + rg;
            float inv = 1.f / sDen[row];
#pragma unroll
            for (int dt = 0; dt < 6; ++dt) {
                int col = 96 * wid + 16 * dt + l15;
                Hp[(rowbase + row) * HHn + col] = f2bf(o[rt][dt][rg] * inv);
            }
        }
}

// ---------------------------------------------------------------------------
// Kernel 3: LN(g1,be1)+relu+dot(W2)+b2+mask -> approx token_scores (bf16 Hp).
// Also zeroes the patch-list counter (runs before span_flag).
// ---------------------------------------------------------------------------
__global__ __launch_bounds__(256) void ln_score_kernel(
    const ushortT* __restrict__ Hp, const float* __restrict__ g1, const float* __restrict__ be1,
    const float* __restrict__ W2, const float* __restrict__ b2,
    const int* __restrict__ am, float* __restrict__ scores, int* __restrict__ count)
{
    if (blockIdx.x == 0 && threadIdx.x == 0) *count = 0;
    const int row  = blockIdx.x * 4 + (threadIdx.x >> 6);
    const int lane = threadIdx.x & 63;
    const ushortT* x = Hp + (size_t)row * HHn;
    float v[6];
#pragma unroll
    for (int j = 0; j < 6; ++j) v[j] = bf2f(x[lane + 64 * j]);
    float s = 0.f;
#pragma unroll
    for (int j = 0; j < 6; ++j) s += v[j];
#pragma unroll
    for (int off = 32; off > 0; off >>= 1) s += __shfl_xor(s, off, 64);
    const float mean = s * (1.0f / 384.0f);
    float q = 0.f;
#pragma unroll
    for (int j = 0; j < 6; ++j) { float d = v[j] - mean; q += d * d; }
#pragma unroll
    for (int off = 32; off > 0; off >>= 1) q += __shfl_xor(q, off, 64);
    const float rstd = rsqrtf(q * (1.0f / 384.0f) + 1e-5f);
    float part = 0.f;
#pragma unroll
    for (int j = 0; j < 6; ++j) {
        int d = lane + 64 * j;
        float h = (v[j] - mean) * rstd * g1[d] + be1[d];
        h = fmaxf(h, 0.f);
        part += h * W2[d];
    }
#pragma unroll
    for (int off = 32; off > 0; off >>= 1) part += __shfl_xor(part, off, 64);
    if (lane == 0) {
        float scv = part + b2[0];
        if (am[row] == 0) scv = -10000.0f;
        scores[row] = scv;
    }
}

// ---------------------------------------------------------------------------
// Kernel 4 (phase B): approx span scan; flag tokens of every span within
// EPS_PATCH of the approx best; append flagged tokens to the patch list.
// ---------------------------------------------------------------------------
__global__ __launch_bounds__(256) void span_flag_kernel(
    const float* __restrict__ scores, const int* __restrict__ am,
    int* __restrict__ list, int* __restrict__ count)
{
    __shared__ float cum[Sn + 1];
    __shared__ float psum[257];
    __shared__ float bval[256];
    __shared__ int   sred[256];
    __shared__ int   sInfo[1];
    __shared__ float sBest;
    __shared__ unsigned char sflag[Sn];

    const int b = blockIdx.x, tid = threadIdx.x;
    for (int i = tid; i < Sn; i += 256) sflag[i] = 0;

    int vl = 0;
    for (int i = tid; i < Sn; i += 256) vl += am[b * Sn + i];
    sred[tid] = vl;
    __syncthreads();
    if (tid == 0) { int t = 0; for (int i = 0; i < 256; ++i) t += sred[i]; sInfo[0] = t; }
    __syncthreads();
    const int valid_len = sInfo[0];

    float loc[8]; float tot = 0.f;
#pragma unroll
    for (int k2 = 0; k2 < 8; ++k2) { loc[k2] = scores[b * Sn + tid * 8 + k2]; tot += loc[k2]; }
    psum[tid + 1] = tot;
    __syncthreads();
    if (tid == 0) {
        psum[0] = 0.f;
        float r = 0.f;
        for (int i = 1; i <= 256; ++i) { float t = psum[i]; psum[i] = r + t; r += t; }
    }
    __syncthreads();
    {
        float r = (tid == 0) ? 0.f : psum[tid];
        if (tid == 0) cum[0] = 0.f;
#pragma unroll
        for (int k2 = 0; k2 < 8; ++k2) { r += loc[k2]; cum[tid * 8 + k2 + 1] = r; }
    }
    __syncthreads();

    float bv = -3.0e30f;
    for (int flat = tid; flat < 18 * Sn; flat += 256) {
        int l = flat >> 11, st = flat & (Sn - 1), L = 3 + l, end = st + L;
        float val;
        if (end <= valid_len) {
            int ec = end < Sn ? end : Sn;
            val = (cum[ec] - cum[st]) / (float)L + (0.01f * (float)L) / 20.0f;
        } else val = -1.0e30f;
        if (val > bv) bv = val;
    }
    bval[tid] = bv;
    __syncthreads();
    if (tid == 0) {
        float best = bval[0];
        for (int i = 1; i < 256; ++i) if (bval[i] > best) best = bval[i];
        sBest = best;
    }
    __syncthreads();

    if (valid_len > 3) {
        const float thr = sBest - EPS_PATCH;
        for (int flat = tid; flat < 18 * Sn; flat += 256) {
            int l = flat >> 11, st = flat & (Sn - 1), L = 3 + l, end = st + L;
            if (end <= valid_len) {
                int ec = end < Sn ? end : Sn;
                float val = (cum[ec] - cum[st]) / (float)L + (0.01f * (float)L) / 20.0f;
                if (val >= thr)
                    for (int t = st; t < end; ++t) sflag[t] = 1;
            }
        }
        __syncthreads();
        for (int t = tid; t < Sn; t += 256)
            if (sflag[t]) { int idx = atomicAdd(count, 1); list[idx] = (b << 16) | t; }
    }
}

// ---------------------------------------------------------------------------
// Kernel 5 (phase C): exact fp32 recompute of flagged tokens' scores.
// q from X@Wq (fp32); k and U reconstructed from bf16 hi+lo (rel err 2^-18).
// ---------------------------------------------------------------------------
static __device__ __forceinline__ float block_sum256(float v, float* sws, int tid)
{
#pragma unroll
    for (int off = 32; off > 0; off >>= 1) v += __shfl_xor(v, off, 64);
    __syncthreads();
    if ((tid & 63) == 0) sws[tid >> 6] = v;
    __syncthreads();
    return sws[0] + sws[1] + sws[2] + sws[3];
}

__global__ __launch_bounds__(256) void patch_kernel(
    const int* __restrict__ list, const int* __restrict__ count,
    const float* __restrict__ X, const float* __restrict__ Wq, const float* __restrict__ bq,
    const ushortT* __restrict__ Khi, const ushortT* __restrict__ Klo,
    const ushortT* __restrict__ Uthi, const ushortT* __restrict__ Utlo,
    const float* __restrict__ g1, const float* __restrict__ be1,
    const float* __restrict__ W2, const float* __restrict__ b2,
    const int* __restrict__ am, float* __restrict__ scores)
{
    __shared__ float sx[Hn];
    __shared__ float sq[HHn];
    __shared__ float sp[Sn];
    __shared__ float sws[4];
    const int tid = threadIdx.x;
    const int n = *count;

    for (int li = blockIdx.x; li < n; li += gridDim.x) {
        int e = list[li];
        int b = e >> 16, t = e & 0xffff;
        __syncthreads();
        for (int d = tid; d < Hn; d += 256) sx[d] = X[((size_t)b * Sn + t) * Hn + d];
        __syncthreads();
        for (int d = tid; d < HHn; d += 256) {
            float a = bq[d];
            for (int k = 0; k < Hn; ++k) a += sx[k] * Wq[(size_t)k * HHn + d];
            sq[d] = a;
        }
        __syncthreads();
        float dpart = 0.f;
        for (int j = tid; j < Sn; j += 256) {
            float p = 0.f;
            if (am[b * Sn + j] != 0) {
                const ushortT* kh = &Khi[((size_t)b * Sn + j) * HHn];
                const ushortT* kl = &Klo[((size_t)b * Sn + j) * HHn];
                float s = 0.f;
                for (int d = 0; d < HHn; ++d) s += sq[d] * (bf2f(kh[d]) + bf2f(kl[d]));
                p = expf(s * SCALE);
            }
            sp[j] = p; dpart += p;
        }
        const float den = block_sum256(dpart, sws, tid);

        float cown[2] = {0.f, 0.f};
        {
            int ii = 0;
            for (int d = tid; d < HHn; d += 256, ++ii) {
                const ushortT* uh = &Uthi[((size_t)b * HHn + d) * Sn];
                const ushortT* ul = &Utlo[((size_t)b * HHn + d) * Sn];
                float c = 0.f;
                for (int j = 0; j < Sn; ++j) c += sp[j] * (bf2f(uh[j]) + bf2f(ul[j]));
                cown[ii] = c / den;
            }
        }
        float ssum = cown[0] + cown[1];
        const float mean = block_sum256(ssum, sws, tid) * (1.0f / 384.0f);
        float vsum = 0.f;
        {
            int ii = 0;
            for (int d = tid; d < HHn; d += 256, ++ii) {
                float dv = cown[ii] - mean; vsum += dv * dv;
            }
        }
        const float var = block_sum256(vsum, sws, tid) * (1.0f / 384.0f);
        const float rstd = rsqrtf(var + 1e-5f);
        float spart = 0.f;
        {
            int ii = 0;
            for (int d = tid; d < HHn; d += 256, ++ii) {
                float h = (cown[ii] - mean) * rstd * g1[d] + be1[d];
                h = fmaxf(h, 0.f);
                spart += h * W2[d];
            }
        }
        const float sc = block_sum256(spart, sws, tid) + b2[0];
        if (tid == 0)
            scores[b * Sn + t] = (am[b * Sn + t] != 0) ? sc : -10000.0f;
        __syncthreads();
    }
}

// ---------------------------------------------------------------------------
// Kernel 6 (phase D): final span argmax (patched scores) + pooling.
// ---------------------------------------------------------------------------
__global__ __launch_bounds__(256) void span_pool_kernel(
    const float* __restrict__ scores, const int* __restrict__ am,
    const float* __restrict__ X, float* __restrict__ pooled)
{
    __shared__ float cum[Sn + 1];
    __shared__ float psum[257];
    __shared__ float bval[256];
    __shared__ int   bidx[256];
    __shared__ int   sred[256];
    __shared__ int   sInfo[2];

    const int b = blockIdx.x, tid = threadIdx.x;

    int vl = 0;
    for (int i = tid; i < Sn; i += 256) vl += am[b * Sn + i];
    sred[tid] = vl;
    __syncthreads();
    if (tid == 0) { int t = 0; for (int i = 0; i < 256; ++i) t += sred[i]; sInfo[0] = t; }
    __syncthreads();
    const int valid_len = sInfo[0];

    float loc[8]; float tot = 0.f;
#pragma unroll
    for (int k2 = 0; k2 < 8; ++k2) { loc[k2] = scores[b * Sn + tid * 8 + k2]; tot += loc[k2]; }
    psum[tid + 1] = tot;
    __syncthreads();
    if (tid == 0) {
        psum[0] = 0.f;
        float r = 0.f;
        for (int i = 1; i <= 256; ++i) { float t = psum[i]; psum[i] = r + t; r += t; }
    }
    __syncthreads();
    {
        float r = (tid == 0) ? 0.f : psum[tid];
        if (tid == 0) cum[0] = 0.f;
#pragma unroll
        for (int k2 = 0; k2 < 8; ++k2) { r += loc[k2]; cum[tid * 8 + k2 + 1] = r; }
    }
    __syncthreads();

    float bv = -3.0e30f; int bi = 0x7fffffff;
    for (int flat = tid; flat < 18 * Sn; flat += 256) {
        int l  = flat >> 11;
        int st = flat & (Sn - 1);
        int L  = 3 + l;
        int end = st + L;
        float val;
        if (end <= valid_len) {
            int ec = end < Sn ? end : Sn;
            val = (cum[ec] - cum[st]) / (float)L + (0.01f * (float)L) / 20.0f;
        } else val = -1.0e30f;
        if (val > bv) { bv = val; bi = flat; }
    }
    bval[tid] = bv; bidx[tid] = bi;
    __syncthreads();
    if (tid == 0) {
        float best = bval[0]; int besti = bidx[0];
        for (int i = 1; i < 256; ++i) {
            if (bval[i] > best || (bval[i] == best && bidx[i] < besti)) {
                best = bval[i]; besti = bidx[i];
            }
        }
        int st, len;
        if (valid_len <= 3) { st = 0; len = valid_len; }
        else { int l = besti >> 11; st = besti & (Sn - 1); len = 3 + l; }
        sInfo[0] = st; sInfo[1] = len;
    }
    __syncthreads();
    const int st = sInfo[0], len = sInfo[1];
    for (int d = tid; d < Hn; d += 256) {
        float s2 = 0.f;
        for (int i = 0; i < len; ++i) s2 += X[((size_t)b * Sn + st + i) * Hn + d];
        pooled[b * Hn + d] = s2 / ((float)len + 1e-6f);
    }
}

// ---------------------------------------------------------------------------
// Kernel 7: head (unchanged from round 1).
// ---------------------------------------------------------------------------
__global__ __launch_bounds__(384) void head_kernel(
    const float* __restrict__ pooled,
    const float* __restrict__ Wc1, const float* __restrict__ bc1,
    const float* __restrict__ g2, const float* __restrict__ be2,
    const float* __restrict__ Wc2, const float* __restrict__ bc2,
    const float* __restrict__ Mint,
    const float* __restrict__ Wcls, const float* __restrict__ bcls,
    const float* __restrict__ X, float* __restrict__ out)
{
    __shared__ float sp[768];
    __shared__ float sh[384];
    __shared__ float scs[64];
    __shared__ float scp[64];
    __shared__ float red[6];
    __shared__ float stat;

    const int b = blockIdx.x, tid = threadIdx.x;
    sp[tid]       = pooled[b * Hn + tid];
    sp[tid + 384] = pooled[b * Hn + 384 + tid];
    __syncthreads();

    float z = bc1[tid];
    for (int k2 = 0; k2 < Hn; ++k2) z += sp[k2] * Wc1[(size_t)k2 * HHn + tid];

    float s = z;
#pragma unroll
    for (int off = 32; off > 0; off >>= 1) s += __shfl_xor(s, off, 64);
    if ((tid & 63) == 0) red[tid >> 6] = s;
    __syncthreads();
    if (tid == 0) stat = (red[0] + red[1] + red[2] + red[3] + red[4] + red[5]) * (1.0f / 384.0f);
    __syncthreads();
    const float mean = stat;
    float dv = z - mean;
    float qq = dv * dv;
#pragma unroll
    for (int off = 32; off > 0; off >>= 1) qq += __shfl_xor(qq, off, 64);
    if ((tid & 63) == 0) red[tid >> 6] = qq;
    __syncthreads();
    if (tid == 0) stat = (red[0] + red[1] + red[2] + red[3] + red[4] + red[5]) * (1.0f / 384.0f);
    __syncthreads();
    const float rstd = rsqrtf(stat + 1e-5f);
    float h = fmaxf(dv * rstd * g2[tid] + be2[tid], 0.f);
    sh[tid] = h;
    __syncthreads();
    if (tid < 64) {
        float c = bc2[tid];
        for (int k2 = 0; k2 < HHn; ++k2) c += sh[k2] * Wc2[k2 * 64 + tid];
        scs[tid] = c;
    }
    __syncthreads();
    if (tid < 64) {
        float a2 = scs[tid];
        for (int c2 = 0; c2 < 64; ++c2) {
            float m   = 0.5f * (Mint[c2 * 64 + tid] + Mint[tid * 64 + c2]);
            float sym = 1.0f / (1.0f + expf(-m));
            a2 += scs[c2] * sym;
        }
        scp[tid] = 1.0f / (1.0f + expf(-a2));
    }
    __syncthreads();
    if (tid < 4) {
        float lg = bcls[tid];
        for (int c2 = 0; c2 < 64; ++c2) lg += scp[c2] * Wcls[c2 * 4 + tid];
        const float* cls = X + (size_t)b * Sn * Hn;
        for (int d2 = 0; d2 < Hn; ++d2) lg += cls[d2] * Wcls[(64 + d2) * 4 + tid];
        out[b * 4 + tid] = lg;
    }
}

// ---------------------------------------------------------------------------
extern "C" void kernel_launch(void* const* d_in, const int* in_sizes, int n_in,
                              void* d_out, int out_size, void* d_ws, size_t ws_size,
                              hipStream_t stream)
{
    const float* X    = (const float*)d_in[0];
    const int*   am   = (const int*)  d_in[1];
    const float* Wq   = (const float*)d_in[2];
    const float* bq   = (const float*)d_in[3];
    const float* Wk   = (const float*)d_in[4];
    const float* bk   = (const float*)d_in[5];
    const float* W1   = (const float*)d_in[6];
    const float* b1   = (const float*)d_in[7];
    const float* g1   = (const float*)d_in[8];
    const float* be1  = (const float*)d_in[9];
    const float* W2   = (const float*)d_in[10];
    const float* b2   = (const float*)d_in[11];
    const float* Wc1  = (const float*)d_in[12];
    const float* bc1  = (const float*)d_in[13];
    const float* g2   = (const float*)d_in[14];
    const float* be2  = (const float*)d_in[15];
    const float* Wc2  = (const float*)d_in[16];
    const float* bc2  = (const float*)d_in[17];
    const float* Mint = (const float*)d_in[18];
    const float* Wcls = (const float*)d_in[19];
    const float* bcls = (const float*)d_in[20];

    const size_t NTb = (size_t)Bn * Sn * HHn;   // 12,582,912 elems
    ushortT* Qhi  = (ushortT*)d_ws;
    ushortT* Khi  = Qhi  + NTb;
    ushortT* Klo  = Khi  + NTb;
    ushortT* Uthi = Klo  + NTb;
    ushortT* Utlo = Uthi + NTb;
    float* scores = (float*)(Utlo + NTb);
    float* pooled = scores + (size_t)Bn * Sn;
    int* list     = (int*)(pooled + (size_t)Bn * Hn);
    int* count    = list + Bn * Sn;
    ushortT* Hp   = Qhi;   // alias: exact row correspondence, block-local
    // total ws use ~126.1 MB

    proj_gemm<<<dim3(256, 3, 3), 256, 0, stream>>>(X, Wq, bq, Wk, bk, W1, b1,
                                                   Qhi, Khi, Klo, Uthi, Utlo);
    attn_mfma<<<dim3(Sn / 64, Bn), 256, 0, stream>>>(Qhi, Khi, Uthi, am, Hp);
    ln_score_kernel<<<(Bn * Sn) / 4, 256, 0, stream>>>(Hp, g1, be1, W2, b2, am, scores, count);
    span_flag_kernel<<<Bn, 256, 0, stream>>>(scores, am, list, count);
    patch_kernel<<<1024, 256, 0, stream>>>(list, count, X, Wq, bq, Khi, Klo, Uthi, Utlo,
                                           g1, be1, W2, b2, am, scores);
    span_pool_kernel<<<Bn, 256, 0, stream>>>(scores, am, X, pooled);
    head_kernel<<<Bn, 384, 0, stream>>>(pooled, Wc1, bc1, g2, be2, Wc2, bc2,
                                        Mint, Wcls, bcls, X, (float*)d_out);
}

// Round 4
// 1581.398 us; speedup vs baseline: 2.6695x; 1.5329x over previous
//
#include <hip/hip_runtime.h>
#include <hip/hip_bf16.h>

#define Bn  16
#define Sn  2048
#define Hn  768
#define HHn 384

typedef unsigned short ushortT;
typedef unsigned int u32;
typedef __attribute__((ext_vector_type(8))) short short8;
typedef __attribute__((ext_vector_type(4))) float f32x4;

static constexpr float SCALE = 0.051031036307982884f; // 1/sqrt(384)
static constexpr float EPS_PATCH = 0.02f;             // ~40 sigma of bf16 path error

static __device__ __forceinline__ float bf2f(ushortT u) {
    return __uint_as_float(((unsigned int)u) << 16);
}
static __device__ __forceinline__ ushortT f2bf(float f) {
    __hip_bfloat16 h = __float2bfloat16(f);
    return *reinterpret_cast<ushortT*>(&h);
}

// async 16B global->LDS DMA (lds dst = wave-uniform base + lane*16)
static __device__ __forceinline__ void gld16(const void* g, void* l) {
    __builtin_amdgcn_global_load_lds(
        (const __attribute__((address_space(1))) u32*)g,
        (__attribute__((address_space(3))) u32*)l, 16, 0, 0);
}
// copy 24576 bytes global->LDS, layout-preserving (linear)
static __device__ __forceinline__ void stage24k(const ushortT* g, unsigned char* l, int tid) {
    const int wid = tid >> 6, lane = tid & 63;
    const unsigned char* gp = (const unsigned char*)g;
#pragma unroll
    for (int i = 0; i < 6; ++i) {
        int blk = i * 4 + wid;                       // 1024B block index 0..23
        gld16(gp + blk * 1024 + lane * 16, l + blk * 1024);
    }
}

// ---------------------------------------------------------------------------
// Kernel 1: projection GEMM (fp32 compute).
// Outputs (bf16):
//   Qhi: row-major [b*Sn+s][384]
//   Kp/Kplo: swizzled K tiles: ((b*32+kt)*64+key)*384 + (c^(key&7))*8 + e
//            where dim = c*8+e  (LDS-image for attn; hi+lo for patch)
//   Up/Uplo: swizzled U 32-key chunks: ((b*64+kc)*384+dim)*32 + (k8^(dim&3))*8 + e
//            where key = kc*32 + k8*8 + e
// ---------------------------------------------------------------------------
__global__ __launch_bounds__(256) void proj_gemm(
    const float* __restrict__ X,
    const float* __restrict__ Wq, const float* __restrict__ bq,
    const float* __restrict__ Wk, const float* __restrict__ bk,
    const float* __restrict__ W1, const float* __restrict__ b1,
    ushortT* __restrict__ Qhi, ushortT* __restrict__ Khi, ushortT* __restrict__ Klo,
    ushortT* __restrict__ Uhi, ushortT* __restrict__ Ulo)
{
    const float* W; const float* bias;
    const int wsel = blockIdx.z;
    if (wsel == 0)      { W = Wq; bias = bq; }
    else if (wsel == 1) { W = Wk; bias = bk; }
    else                { W = W1; bias = b1; }

    const int m0  = blockIdx.x * 128;
    const int n0  = blockIdx.y * 128;
    const int tid = threadIdx.x;
    const int im  = tid >> 4;
    const int jn  = tid & 15;

    __shared__ __align__(16) float sA[16][132];
    __shared__ __align__(16) float sB[16][132];

    float acc[8][8];
#pragma unroll
    for (int i = 0; i < 8; ++i)
#pragma unroll
        for (int j = 0; j < 8; ++j) acc[i][j] = 0.f;

    for (int k0 = 0; k0 < Hn; k0 += 16) {
        __syncthreads();
#pragma unroll
        for (int it = 0; it < 2; ++it) {
            int f = tid + 256 * it;
            int row = f >> 2, k4 = (f & 3) * 4;
            float4 v = *reinterpret_cast<const float4*>(
                &X[(size_t)(m0 + row) * Hn + k0 + k4]);
            sA[k4 + 0][row] = v.x; sA[k4 + 1][row] = v.y;
            sA[k4 + 2][row] = v.z; sA[k4 + 3][row] = v.w;
        }
#pragma unroll
        for (int it = 0; it < 2; ++it) {
            int f = tid + 256 * it;
            int kk = f >> 5, n4 = (f & 31) * 4;
            *reinterpret_cast<float4*>(&sB[kk][n4]) =
                *reinterpret_cast<const float4*>(&W[(size_t)(k0 + kk) * HHn + n0 + n4]);
        }
        __syncthreads();
#pragma unroll
        for (int kk = 0; kk < 16; ++kk) {
            float a[8], bb[8];
            *reinterpret_cast<float4*>(&a[0])  = *reinterpret_cast<const float4*>(&sA[kk][im * 8]);
            *reinterpret_cast<float4*>(&a[4])  = *reinterpret_cast<const float4*>(&sA[kk][im * 8 + 4]);
            *reinterpret_cast<float4*>(&bb[0]) = *reinterpret_cast<const float4*>(&sB[kk][jn * 8]);
            *reinterpret_cast<float4*>(&bb[4]) = *reinterpret_cast<const float4*>(&sB[kk][jn * 8 + 4]);
#pragma unroll
            for (int i = 0; i < 8; ++i)
#pragma unroll
                for (int j = 0; j < 8; ++j) acc[i][j] += a[i] * bb[j];
        }
    }

    if (wsel == 0) {
#pragma unroll
        for (int i = 0; i < 8; ++i) {
            size_t m = (size_t)m0 + im * 8 + i;
            int nb = n0 + jn * 8;
            short8 hv;
#pragma unroll
            for (int j = 0; j < 8; ++j) hv[j] = (short)f2bf(acc[i][j] + bias[nb + j]);
            *reinterpret_cast<short8*>(&Qhi[m * HHn + nb]) = hv;
        }
    } else if (wsel == 1) {
        const int bb = m0 >> 11;
        const int bibase = m0 & 2047;
#pragma unroll
        for (int i = 0; i < 8; ++i) {
            int kg = bibase + im * 8 + i;
            int kt = kg >> 6, key = kg & 63;
            size_t rowoff = ((size_t)(bb * 32 + kt) * 64 + key) * 384;
            int sc_ = ((n0 >> 3) + jn) ^ (key & 7);
            short8 hv, lv;
#pragma unroll
            for (int j = 0; j < 8; ++j) {
                float v = acc[i][j] + bias[n0 + jn * 8 + j];
                ushortT hb = f2bf(v);
                hv[j] = (short)hb;
                lv[j] = (short)f2bf(v - bf2f(hb));
            }
            *reinterpret_cast<short8*>(&Khi[rowoff + sc_ * 8]) = hv;
            *reinterpret_cast<short8*>(&Klo[rowoff + sc_ * 8]) = lv;
        }
    } else {
        const int bb = m0 >> 11;
        const int tib = (m0 & 2047) + im * 8;     // token (key) index in batch
        const int kc = tib >> 5, k8 = (tib >> 3) & 3;
        const size_t cbase = (size_t)(bb * 64 + kc) * 384;
#pragma unroll
        for (int j = 0; j < 8; ++j) {
            int dim = n0 + jn * 8 + j;
            int sk = k8 ^ (dim & 3);
            float bv = bias[dim];
            short8 hv, lv;
#pragma unroll
            for (int i = 0; i < 8; ++i) {
                float v = acc[i][j] + bv;
                ushortT hb = f2bf(v);
                hv[i] = (short)hb;
                lv[i] = (short)f2bf(v - bf2f(hb));
            }
            size_t off = (cbase + dim) * 32 + sk * 8;
            *reinterpret_cast<short8*>(&Uhi[off]) = hv;
            *reinterpret_cast<short8*>(&Ulo[off]) = lv;
        }
    }
}

// ---------------------------------------------------------------------------
// Kernel 2: bf16 MFMA flash attention, v3 (fixed: rotating buffers held as
// integer LDS byte-offsets, not a pointer array — gfx950 rejects addrspacecast
// static initializers).
// Hp = softmax(QK^T*SCALE, key-masked) @ U, with U = X@W1+b1.
// 256 thr (4 waves), q-tile 64, 2 blocks/CU (LDS exactly 81920B).
// 3 rotating 24KB buffers (K halves / U chunks) filled by global_load_lds
// from proj's swizzled LDS-image layouts; P XOR-swizzled; Q frags + den in regs.
// QK: wave w owns rows 16w x all 64 cols.  PV: wave w owns dims 96w x all rows.
// Hp aliases Qhi (Q read once at start, same rows) -> no __restrict__ on those.
// ---------------------------------------------------------------------------
__global__ __launch_bounds__(256, 2) void attn_mfma(
    const ushortT* Qg, const ushortT* __restrict__ Kp, const ushortT* __restrict__ Up,
    const int* __restrict__ am, ushortT* Hp)
{
    __shared__ __align__(16) unsigned char smem[81920];
    ushortT* sP = (ushortT*)(smem + 73728);   // 64 rows x 128B, chunk-XOR by row&7

    const int tid  = threadIdx.x;
    const int wid  = tid >> 6;
    const int lane = tid & 63;
    const int quad = lane >> 4;
    const int l15  = lane & 15;
    const int b    = blockIdx.y;
    const int q0   = blockIdx.x * 64;
    const size_t rowbase = (size_t)b * Sn + q0;
    const int* amb = am + b * Sn;

    const ushortT* Kbase = Kp + (size_t)b * 32 * 64 * 384;  // 24576 shorts per kt tile
    const ushortT* Ubase = Up + (size_t)b * 64 * 12288;     // 12288 shorts per kc chunk

    // Q fragments: wave rows r0..r0+15, all 384 dims (row-major global, 16B reads)
    const int r0 = wid * 16;
    short8 qf[12];
#pragma unroll
    for (int ks = 0; ks < 12; ++ks)
        qf[ks] = *reinterpret_cast<const short8*>(
            &Qg[(rowbase + r0 + l15) * HHn + ks * 32 + quad * 8]);

    f32x4 o[4][6];
#pragma unroll
    for (int rt = 0; rt < 4; ++rt)
#pragma unroll
        for (int dt = 0; dt < 6; ++dt) o[rt][dt] = (f32x4){0.f, 0.f, 0.f, 0.f};
    float denacc[4] = {0.f, 0.f, 0.f, 0.f};

    // rotating buffer byte-offsets into smem
    int ia = 0, ibx = 24576, ic = 49152;

    // preload K halves of kt=0
    stage24k(Kbase, smem + ia, tid);
    stage24k(Kbase + 12288, smem + ibx, tid);
    __syncthreads();

    const int d0 = wid * 96;

    for (int kt = 0; kt < 32; ++kt) {
        // U chunk 0 of this kt -> free buffer (flight covers whole QK phase)
        stage24k(Ubase + (size_t)(kt * 2) * 12288, smem + ic, tid);

        // ---- QK^T: rows r0..r0+15 x cols 0..63 ----
        f32x4 sc[4];
#pragma unroll
        for (int ct = 0; ct < 4; ++ct) sc[ct] = (f32x4){0.f, 0.f, 0.f, 0.f};
#pragma unroll
        for (int ks = 0; ks < 12; ++ks) {
#pragma unroll
            for (int ct = 0; ct < 4; ++ct) {
                int kl = (ct & 1) * 16 + l15;   // key within half-tile (0..31)
                const unsigned char* Bk = smem + ((ct < 2) ? ia : ibx);
                short8 bf = *reinterpret_cast<const short8*>(
                    Bk + kl * 768 + ((((ks << 2) + quad) ^ (kl & 7)) << 4));
                sc[ct] = __builtin_amdgcn_mfma_f32_16x16x32_bf16(qf[ks], bf, sc[ct], 0, 0, 0);
            }
        }

        // ---- exp -> P (XOR layout), den accumulate (wave-local rows) ----
        float dp[4] = {0.f, 0.f, 0.f, 0.f};
#pragma unroll
        for (int ct = 0; ct < 4; ++ct) {
            int col = ct * 16 + l15;
            float mval = (amb[kt * 64 + col] != 0) ? 1.f : 0.f;
#pragma unroll
            for (int rg = 0; rg < 4; ++rg) {
                int row = r0 + quad * 4 + rg;
                float p = __expf(sc[ct][rg] * SCALE) * mval;
                sP[row * 64 + (((col >> 3) ^ (row & 7)) << 3) + (col & 7)] = f2bf(p);
                dp[rg] += p;
            }
        }
#pragma unroll
        for (int off = 1; off < 16; off <<= 1)
#pragma unroll
            for (int rg = 0; rg < 4; ++rg) dp[rg] += __shfl_xor(dp[rg], off, 16);
#pragma unroll
        for (int rg = 0; rg < 4; ++rg) denacc[rg] += dp[rg];

        __syncthreads();   // b1: U0 ready, P visible, K buffers free

        stage24k(Ubase + (size_t)(kt * 2 + 1) * 12288, smem + ia, tid);  // U1
        if (kt < 31) stage24k(Kbase + (size_t)(kt + 1) * 24576, smem + ibx, tid); // next Kh0

        // ---- PV chunk 0 (keys kt*64 .. +31) from buffer ic ----
        {
            const unsigned char* Bu = smem + ic;
            short8 pa[4];
#pragma unroll
            for (int rt = 0; rt < 4; ++rt)
                pa[rt] = *reinterpret_cast<const short8*>(
                    &sP[(16 * rt + l15) * 64 + ((quad ^ (l15 & 7)) << 3)]);
#pragma unroll
            for (int dt = 0; dt < 6; ++dt) {
                short8 u = *reinterpret_cast<const short8*>(
                    Bu + (d0 + 16 * dt + l15) * 64 + ((quad ^ (l15 & 3)) << 4));
#pragma unroll
                for (int rt = 0; rt < 4; ++rt)
                    o[rt][dt] = __builtin_amdgcn_mfma_f32_16x16x32_bf16(pa[rt], u, o[rt][dt], 0, 0, 0);
            }
        }
        __syncthreads();   // b2: U1 + next-Kh0 ready, buffer ic free

        if (kt < 31) stage24k(Kbase + (size_t)(kt + 1) * 24576 + 12288, smem + ic, tid); // next Kh1

        // ---- PV chunk 1 (keys kt*64+32 .. +63) from buffer ia ----
        {
            const unsigned char* Bu = smem + ia;
            short8 pa[4];
#pragma unroll
            for (int rt = 0; rt < 4; ++rt)
                pa[rt] = *reinterpret_cast<const short8*>(
                    &sP[(16 * rt + l15) * 64 + (((4 + quad) ^ (l15 & 7)) << 3)]);
#pragma unroll
            for (int dt = 0; dt < 6; ++dt) {
                short8 u = *reinterpret_cast<const short8*>(
                    Bu + (d0 + 16 * dt + l15) * 64 + ((quad ^ (l15 & 3)) << 4));
#pragma unroll
                for (int rt = 0; rt < 4; ++rt)
                    o[rt][dt] = __builtin_amdgcn_mfma_f32_16x16x32_bf16(pa[rt], u, o[rt][dt], 0, 0, 0);
            }
        }
        __syncthreads();   // b3: next-Kh1 ready, buffer ia free

        int t = ia; ia = ibx; ibx = ic; ic = t;   // rotate
    }

    // ---- epilogue: den exchange, Hp staged in LDS, wide coalesced store ----
    float* sDenF = (float*)smem;
    if (l15 == 0) {
#pragma unroll
        for (int rg = 0; rg < 4; ++rg) sDenF[r0 + quad * 4 + rg] = denacc[rg];
    }
    __syncthreads();
    ushortT* sHp = (ushortT*)(smem + 512);        // 64 x 384 bf16 = 48KB
#pragma unroll
    for (int rt = 0; rt < 4; ++rt)
#pragma unroll
        for (int rg = 0; rg < 4; ++rg) {
            int row = rt * 16 + quad * 4 + rg;
            float inv = 1.f / sDenF[row];
#pragma unroll
            for (int dt = 0; dt < 6; ++dt)
                sHp[row * 384 + d0 + dt * 16 + l15] = f2bf(o[rt][dt][rg] * inv);
        }
    __syncthreads();
#pragma unroll
    for (int i = 0; i < 12; ++i) {
        int idx = i * 256 + tid;
        *reinterpret_cast<uint4*>(&Hp[rowbase * HHn + idx * 8]) =
            *reinterpret_cast<const uint4*>(&sHp[idx * 8]);
    }
}

// ---------------------------------------------------------------------------
// Kernel 3: LN(g1,be1)+relu+dot(W2)+b2+mask -> approx token_scores (bf16 Hp).
// Also zeroes the patch-list counter.
// ---------------------------------------------------------------------------
__global__ __launch_bounds__(256) void ln_score_kernel(
    const ushortT* __restrict__ Hp, const float* __restrict__ g1, const float* __restrict__ be1,
    const float* __restrict__ W2, const float* __restrict__ b2,
    const int* __restrict__ am, float* __restrict__ scores, int* __restrict__ count)
{
    if (blockIdx.x == 0 && threadIdx.x == 0) *count = 0;
    const int row  = blockIdx.x * 4 + (threadIdx.x >> 6);
    const int lane = threadIdx.x & 63;
    const ushortT* x = Hp + (size_t)row * HHn;
    float v[6];
#pragma unroll
    for (int j = 0; j < 6; ++j) v[j] = bf2f(x[lane + 64 * j]);
    float s = 0.f;
#pragma unroll
    for (int j = 0; j < 6; ++j) s += v[j];
#pragma unroll
    for (int off = 32; off > 0; off >>= 1) s += __shfl_xor(s, off, 64);
    const float mean = s * (1.0f / 384.0f);
    float q = 0.f;
#pragma unroll
    for (int j = 0; j < 6; ++j) { float d = v[j] - mean; q += d * d; }
#pragma unroll
    for (int off = 32; off > 0; off >>= 1) q += __shfl_xor(q, off, 64);
    const float rstd = rsqrtf(q * (1.0f / 384.0f) + 1e-5f);
    float part = 0.f;
#pragma unroll
    for (int j = 0; j < 6; ++j) {
        int d = lane + 64 * j;
        float h = (v[j] - mean) * rstd * g1[d] + be1[d];
        h = fmaxf(h, 0.f);
        part += h * W2[d];
    }
#pragma unroll
    for (int off = 32; off > 0; off >>= 1) part += __shfl_xor(part, off, 64);
    if (lane == 0) {
        float scv = part + b2[0];
        if (am[row] == 0) scv = -10000.0f;
        scores[row] = scv;
    }
}

// ---------------------------------------------------------------------------
// Kernel 4: approx span scan; flag tokens of spans within EPS of approx best.
// ---------------------------------------------------------------------------
__global__ __launch_bounds__(256) void span_flag_kernel(
    const float* __restrict__ scores, const int* __restrict__ am,
    int* __restrict__ list, int* __restrict__ count)
{
    __shared__ float cum[Sn + 1];
    __shared__ float psum[257];
    __shared__ float bval[256];
    __shared__ int   sred[256];
    __shared__ int   sInfo[1];
    __shared__ float sBest;
    __shared__ unsigned char sflag[Sn];

    const int b = blockIdx.x, tid = threadIdx.x;
    for (int i = tid; i < Sn; i += 256) sflag[i] = 0;

    int vl = 0;
    for (int i = tid; i < Sn; i += 256) vl += am[b * Sn + i];
    sred[tid] = vl;
    __syncthreads();
    if (tid == 0) { int t = 0; for (int i = 0; i < 256; ++i) t += sred[i]; sInfo[0] = t; }
    __syncthreads();
    const int valid_len = sInfo[0];

    float loc[8]; float tot = 0.f;
#pragma unroll
    for (int k2 = 0; k2 < 8; ++k2) { loc[k2] = scores[b * Sn + tid * 8 + k2]; tot += loc[k2]; }
    psum[tid + 1] = tot;
    __syncthreads();
    if (tid == 0) {
        psum[0] = 0.f;
        float r = 0.f;
        for (int i = 1; i <= 256; ++i) { float t = psum[i]; psum[i] = r + t; r += t; }
    }
    __syncthreads();
    {
        float r = (tid == 0) ? 0.f : psum[tid];
        if (tid == 0) cum[0] = 0.f;
#pragma unroll
        for (int k2 = 0; k2 < 8; ++k2) { r += loc[k2]; cum[tid * 8 + k2 + 1] = r; }
    }
    __syncthreads();

    float bv = -3.0e30f;
    for (int flat = tid; flat < 18 * Sn; flat += 256) {
        int l = flat >> 11, st = flat & (Sn - 1), L = 3 + l, end = st + L;
        float val;
        if (end <= valid_len) {
            int ec = end < Sn ? end : Sn;
            val = (cum[ec] - cum[st]) / (float)L + (0.01f * (float)L) / 20.0f;
        } else val = -1.0e30f;
        if (val > bv) bv = val;
    }
    bval[tid] = bv;
    __syncthreads();
    if (tid == 0) {
        float best = bval[0];
        for (int i = 1; i < 256; ++i) if (bval[i] > best) best = bval[i];
        sBest = best;
    }
    __syncthreads();

    if (valid_len > 3) {
        const float thr = sBest - EPS_PATCH;
        for (int flat = tid; flat < 18 * Sn; flat += 256) {
            int l = flat >> 11, st = flat & (Sn - 1), L = 3 + l, end = st + L;
            if (end <= valid_len) {
                int ec = end < Sn ? end : Sn;
                float val = (cum[ec] - cum[st]) / (float)L + (0.01f * (float)L) / 20.0f;
                if (val >= thr)
                    for (int t = st; t < end; ++t) sflag[t] = 1;
            }
        }
        __syncthreads();
        for (int t = tid; t < Sn; t += 256)
            if (sflag[t]) { int idx = atomicAdd(count, 1); list[idx] = (b << 16) | t; }
    }
}

// ---------------------------------------------------------------------------
// Kernel 5: exact fp32 recompute of flagged tokens' scores.
// q from X@Wq (fp32); k,U reconstructed from swizzled bf16 hi+lo (rel err 2^-18).
// ---------------------------------------------------------------------------
static __device__ __forceinline__ float block_sum256(float v, float* sws, int tid)
{
#pragma unroll
    for (int off = 32; off > 0; off >>= 1) v += __shfl_xor(v, off, 64);
    __syncthreads();
    if ((tid & 63) == 0) sws[tid >> 6] = v;
    __syncthreads();
    return sws[0] + sws[1] + sws[2] + sws[3];
}

__global__ __launch_bounds__(256) void patch_kernel(
    const int* __restrict__ list, const int* __restrict__ count,
    const float* __restrict__ X, const float* __restrict__ Wq, const float* __restrict__ bq,
    const ushortT* __restrict__ Khi, const ushortT* __restrict__ Klo,
    const ushortT* __restrict__ Uhi, const ushortT* __restrict__ Ulo,
    const float* __restrict__ g1, const float* __restrict__ be1,
    const float* __restrict__ W2, const float* __restrict__ b2,
    const int* __restrict__ am, float* __restrict__ scores)
{
    __shared__ float sx[Hn];
    __shared__ float sq[HHn];
    __shared__ float sp[Sn];
    __shared__ float sws[4];
    const int tid = threadIdx.x;
    const int n = *count;

    for (int li = blockIdx.x; li < n; li += gridDim.x) {
        int e = list[li];
        int b = e >> 16, t = e & 0xffff;
        __syncthreads();
        for (int d = tid; d < Hn; d += 256) sx[d] = X[((size_t)b * Sn + t) * Hn + d];
        __syncthreads();
        for (int d = tid; d < HHn; d += 256) {
            float a = bq[d];
            for (int k = 0; k < Hn; ++k) a += sx[k] * Wq[(size_t)k * HHn + d];
            sq[d] = a;
        }
        __syncthreads();
        float dpart = 0.f;
        for (int j = tid; j < Sn; j += 256) {
            float p = 0.f;
            if (am[b * Sn + j] != 0) {
                int kt = j >> 6, key = j & 63, kk7 = key & 7;
                size_t ro = ((size_t)(b * 32 + kt) * 64 + key) * 384;
                const ushortT* kh = &Khi[ro];
                const ushortT* kl = &Klo[ro];
                float s = 0.f;
                for (int c = 0; c < 48; ++c) {
                    int dbase = (c ^ kk7) << 3;
                    for (int ee = 0; ee < 8; ++ee)
                        s += sq[dbase + ee] * (bf2f(kh[c * 8 + ee]) + bf2f(kl[c * 8 + ee]));
                }
                p = expf(s * SCALE);
            }
            sp[j] = p; dpart += p;
        }
        const float den = block_sum256(dpart, sws, tid);

        float cown[2] = {0.f, 0.f};
        {
            int ii = 0;
            for (int d = tid; d < HHn; d += 256, ++ii) {
                int d3 = d & 3;
                float c = 0.f;
                for (int kc = 0; kc < 64; ++kc) {
                    size_t ub = ((size_t)(b * 64 + kc) * 384 + d) * 32;
                    const ushortT* uh = &Uhi[ub];
                    const ushortT* ul = &Ulo[ub];
                    for (int k8 = 0; k8 < 4; ++k8) {
                        int sk = k8 ^ d3;
                        int j0 = kc * 32 + k8 * 8;
                        for (int ee = 0; ee < 8; ++ee)
                            c += sp[j0 + ee] * (bf2f(uh[sk * 8 + ee]) + bf2f(ul[sk * 8 + ee]));
                    }
                }
                cown[ii] = c / den;
            }
        }
        float ssum = cown[0] + cown[1];
        const float mean = block_sum256(ssum, sws, tid) * (1.0f / 384.0f);
        float vsum = 0.f;
        {
            int ii = 0;
            for (int d = tid; d < HHn; d += 256, ++ii) {
                float dv = cown[ii] - mean; vsum += dv * dv;
            }
        }
        const float var = block_sum256(vsum, sws, tid) * (1.0f / 384.0f);
        const float rstd = rsqrtf(var + 1e-5f);
        float spart = 0.f;
        {
            int ii = 0;
            for (int d = tid; d < HHn; d += 256, ++ii) {
                float h = (cown[ii] - mean) * rstd * g1[d] + be1[d];
                h = fmaxf(h, 0.f);
                spart += h * W2[d];
            }
        }
        const float sc = block_sum256(spart, sws, tid) + b2[0];
        if (tid == 0)
            scores[b * Sn + t] = (am[b * Sn + t] != 0) ? sc : -10000.0f;
        __syncthreads();
    }
}

// ---------------------------------------------------------------------------
// Kernel 6: final span argmax (patched scores) + pooling.
// ---------------------------------------------------------------------------
__global__ __launch_bounds__(256) void span_pool_kernel(
    const float* __restrict__ scores, const int* __restrict__ am,
    const float* __restrict__ X, float* __restrict__ pooled)
{
    __shared__ float cum[Sn + 1];
    __shared__ float psum[257];
    __shared__ float bval[256];
    __shared__ int   bidx[256];
    __shared__ int   sred[256];
    __shared__ int   sInfo[2];

    const int b = blockIdx.x, tid = threadIdx.x;

    int vl = 0;
    for (int i = tid; i < Sn; i += 256) vl += am[b * Sn + i];
    sred[tid] = vl;
    __syncthreads();
    if (tid == 0) { int t = 0; for (int i = 0; i < 256; ++i) t += sred[i]; sInfo[0] = t; }
    __syncthreads();
    const int valid_len = sInfo[0];

    float loc[8]; float tot = 0.f;
#pragma unroll
    for (int k2 = 0; k2 < 8; ++k2) { loc[k2] = scores[b * Sn + tid * 8 + k2]; tot += loc[k2]; }
    psum[tid + 1] = tot;
    __syncthreads();
    if (tid == 0) {
        psum[0] = 0.f;
        float r = 0.f;
        for (int i = 1; i <= 256; ++i) { float t = psum[i]; psum[i] = r + t; r += t; }
    }
    __syncthreads();
    {
        float r = (tid == 0) ? 0.f : psum[tid];
        if (tid == 0) cum[0] = 0.f;
#pragma unroll
        for (int k2 = 0; k2 < 8; ++k2) { r += loc[k2]; cum[tid * 8 + k2 + 1] = r; }
    }
    __syncthreads();

    float bv = -3.0e30f; int bi = 0x7fffffff;
    for (int flat = tid; flat < 18 * Sn; flat += 256) {
        int l  = flat >> 11;
        int st = flat & (Sn - 1);
        int L  = 3 + l;
        int end = st + L;
        float val;
        if (end <= valid_len) {
            int ec = end < Sn ? end : Sn;
            val = (cum[ec] - cum[st]) / (float)L + (0.01f * (float)L) / 20.0f;
        } else val = -1.0e30f;
        if (val > bv) { bv = val; bi = flat; }
    }
    bval[tid] = bv; bidx[tid] = bi;
    __syncthreads();
    if (tid == 0) {
        float best = bval[0]; int besti = bidx[0];
        for (int i = 1; i < 256; ++i) {
            if (bval[i] > best || (bval[i] == best && bidx[i] < besti)) {
                best = bval[i]; besti = bidx[i];
            }
        }
        int st, len;
        if (valid_len <= 3) { st = 0; len = valid_len; }
        else { int l = besti >> 11; st = besti & (Sn - 1); len = 3 + l; }
        sInfo[0] = st; sInfo[1] = len;
    }
    __syncthreads();
    const int st = sInfo[0], len = sInfo[1];
    for (int d = tid; d < Hn; d += 256) {
        float s2 = 0.f;
        for (int i = 0; i < len; ++i) s2 += X[((size_t)b * Sn + st + i) * Hn + d];
        pooled[b * Hn + d] = s2 / ((float)len + 1e-6f);
    }
}

// ---------------------------------------------------------------------------
// Kernel 7: head.
// ---------------------------------------------------------------------------
__global__ __launch_bounds__(384) void head_kernel(
    const float* __restrict__ pooled,
    const float* __restrict__ Wc1, const float* __restrict__ bc1,
    const float* __restrict__ g2, const float* __restrict__ be2,
    const float* __restrict__ Wc2, const float* __restrict__ bc2,
    const float* __restrict__ Mint,
    const float* __restrict__ Wcls, const float* __restrict__ bcls,
    const float* __restrict__ X, float* __restrict__ out)
{
    __shared__ float sp[768];
    __shared__ float sh[384];
    __shared__ float scs[64];
    __shared__ float scp[64];
    __shared__ float red[6];
    __shared__ float stat;

    const int b = blockIdx.x, tid = threadIdx.x;
    sp[tid]       = pooled[b * Hn + tid];
    sp[tid + 384] = pooled[b * Hn + 384 + tid];
    __syncthreads();

    float z = bc1[tid];
    for (int k2 = 0; k2 < Hn; ++k2) z += sp[k2] * Wc1[(size_t)k2 * HHn + tid];

    float s = z;
#pragma unroll
    for (int off = 32; off > 0; off >>= 1) s += __shfl_xor(s, off, 64);
    if ((tid & 63) == 0) red[tid >> 6] = s;
    __syncthreads();
    if (tid == 0) stat = (red[0] + red[1] + red[2] + red[3] + red[4] + red[5]) * (1.0f / 384.0f);
    __syncthreads();
    const float mean = stat;
    float dv = z - mean;
    float qq = dv * dv;
#pragma unroll
    for (int off = 32; off > 0; off >>= 1) qq += __shfl_xor(qq, off, 64);
    if ((tid & 63) == 0) red[tid >> 6] = qq;
    __syncthreads();
    if (tid == 0) stat = (red[0] + red[1] + red[2] + red[3] + red[4] + red[5]) * (1.0f / 384.0f);
    __syncthreads();
    const float rstd = rsqrtf(stat + 1e-5f);
    float h = fmaxf(dv * rstd * g2[tid] + be2[tid], 0.f);
    sh[tid] = h;
    __syncthreads();
    if (tid < 64) {
        float c = bc2[tid];
        for (int k2 = 0; k2 < HHn; ++k2) c += sh[k2] * Wc2[k2 * 64 + tid];
        scs[tid] = c;
    }
    __syncthreads();
    if (tid < 64) {
        float a2 = scs[tid];
        for (int c2 = 0; c2 < 64; ++c2) {
            float m   = 0.5f * (Mint[c2 * 64 + tid] + Mint[tid * 64 + c2]);
            float sym = 1.0f / (1.0f + expf(-m));
            a2 += scs[c2] * sym;
        }
        scp[tid] = 1.0f / (1.0f + expf(-a2));
    }
    __syncthreads();
    if (tid < 4) {
        float lg = bcls[tid];
        for (int c2 = 0; c2 < 64; ++c2) lg += scp[c2] * Wcls[c2 * 4 + tid];
        const float* cls = X + (size_t)b * Sn * Hn;
        for (int d2 = 0; d2 < Hn; ++d2) lg += cls[d2] * Wcls[(64 + d2) * 4 + tid];
        out[b * 4 + tid] = lg;
    }
}

// ---------------------------------------------------------------------------
extern "C" void kernel_launch(void* const* d_in, const int* in_sizes, int n_in,
                              void* d_out, int out_size, void* d_ws, size_t ws_size,
                              hipStream_t stream)
{
    const float* X    = (const float*)d_in[0];
    const int*   am   = (const int*)  d_in[1];
    const float* Wq   = (const float*)d_in[2];
    const float* bq   = (const float*)d_in[3];
    const float* Wk   = (const float*)d_in[4];
    const float* bk   = (const float*)d_in[5];
    const float* W1   = (const float*)d_in[6];
    const float* b1   = (const float*)d_in[7];
    const float* g1   = (const float*)d_in[8];
    const float* be1  = (const float*)d_in[9];
    const float* W2   = (const float*)d_in[10];
    const float* b2   = (const float*)d_in[11];
    const float* Wc1  = (const float*)d_in[12];
    const float* bc1  = (const float*)d_in[13];
    const float* g2   = (const float*)d_in[14];
    const float* be2  = (const float*)d_in[15];
    const float* Wc2  = (const float*)d_in[16];
    const float* bc2  = (const float*)d_in[17];
    const float* Mint = (const float*)d_in[18];
    const float* Wcls = (const float*)d_in[19];
    const float* bcls = (const float*)d_in[20];

    const size_t NTb = (size_t)Bn * Sn * HHn;   // 12,582,912 elems
    ushortT* Qhi  = (ushortT*)d_ws;
    ushortT* Kp   = Qhi + NTb;                  // swizzled K hi
    ushortT* Kplo = Kp  + NTb;                  // swizzled K lo
    ushortT* Upp  = Kplo + NTb;                 // swizzled U hi
    ushortT* Uplo = Upp + NTb;                  // swizzled U lo
    float* scores = (float*)(Uplo + NTb);
    float* pooled = scores + (size_t)Bn * Sn;
    int* list     = (int*)(pooled + (size_t)Bn * Hn);
    int* count    = list + Bn * Sn;
    ushortT* Hp   = Qhi;   // alias: attn reads Q rows before writing same rows

    proj_gemm<<<dim3(256, 3, 3), 256, 0, stream>>>(X, Wq, bq, Wk, bk, W1, b1,
                                                   Qhi, Kp, Kplo, Upp, Uplo);
    attn_mfma<<<dim3(Sn / 64, Bn), 256, 0, stream>>>(Qhi, Kp, Upp, am, Hp);
    ln_score_kernel<<<(Bn * Sn) / 4, 256, 0, stream>>>(Hp, g1, be1, W2, b2, am, scores, count);
    span_flag_kernel<<<Bn, 256, 0, stream>>>(scores, am, list, count);
    patch_kernel<<<1024, 256, 0, stream>>>(list, count, X, Wq, bq, Kp, Kplo, Upp, Uplo,
                                           g1, be1, W2, b2, am, scores);
    span_pool_kernel<<<Bn, 256, 0, stream>>>(scores, am, X, pooled);
    head_kernel<<<Bn, 384, 0, stream>>>(pooled, Wc1, bc1, g2, be2, Wc2, bc2,
                                        Mint, Wcls, bcls, X, (float*)d_out);
}

// Round 5
// 1240.116 us; speedup vs baseline: 3.4042x; 1.2752x over previous
//
#include <hip/hip_runtime.h>
#include <hip/hip_bf16.h>

#define Bn  16
#define Sn  2048
#define Hn  768
#define HHn 384

typedef unsigned short ushortT;
typedef unsigned int u32;
typedef __attribute__((ext_vector_type(8))) short short8;
typedef __attribute__((ext_vector_type(4))) short short4v;
typedef __attribute__((ext_vector_type(4))) float f32x4;

static constexpr float SCALE = 0.051031036307982884f; // 1/sqrt(384)
static constexpr float EPS_PATCH = 0.025f;            // covers approx-score error (bf16 pipeline + Q hi-only MFMA)

static __device__ __forceinline__ float bf2f(ushortT u) {
    return __uint_as_float(((unsigned int)u) << 16);
}
static __device__ __forceinline__ ushortT f2bf(float f) {
    __hip_bfloat16 h = __float2bfloat16(f);
    return *reinterpret_cast<ushortT*>(&h);
}

// async 16B global->LDS DMA (lds dst = wave-uniform base + lane*16)
static __device__ __forceinline__ void gld16(const void* g, void* l) {
    __builtin_amdgcn_global_load_lds(
        (const __attribute__((address_space(1))) u32*)g,
        (__attribute__((address_space(3))) u32*)l, 16, 0, 0);
}
// copy 24576 bytes global->LDS, layout-preserving (linear)
static __device__ __forceinline__ void stage24k(const ushortT* g, unsigned char* l, int tid) {
    const int wid = tid >> 6, lane = tid & 63;
    const unsigned char* gp = (const unsigned char*)g;
#pragma unroll
    for (int i = 0; i < 6; ++i) {
        int blk = i * 4 + wid;                       // 1024B block index 0..23
        gld16(gp + blk * 1024 + lane * 16, l + blk * 1024);
    }
}

// ---------------------------------------------------------------------------
// Kernel 0a: X fp32 -> bf16 hi/lo split arrays.
// ---------------------------------------------------------------------------
__global__ __launch_bounds__(256) void convert_x(
    const float* __restrict__ X, ushortT* __restrict__ Xhi, ushortT* __restrict__ Xlo)
{
    size_t i = ((size_t)blockIdx.x * 256 + threadIdx.x) * 4;
    float4 v = *reinterpret_cast<const float4*>(&X[i]);
    short4v h, l;
    float vv[4] = {v.x, v.y, v.z, v.w};
#pragma unroll
    for (int j = 0; j < 4; ++j) {
        ushortT hb = f2bf(vv[j]);
        h[j] = (short)hb;
        l[j] = (short)f2bf(vv[j] - bf2f(hb));
    }
    *reinterpret_cast<short4v*>(&Xhi[i]) = h;
    *reinterpret_cast<short4v*>(&Xlo[i]) = l;
}

// ---------------------------------------------------------------------------
// Kernel 0b: weights fp32 [768][384] -> transposed bf16 hi/lo [w][n][k] (384x768).
// 110592 threads: t -> (w, kg, n) with n fastest (coalesced reads).
// ---------------------------------------------------------------------------
__global__ __launch_bounds__(256) void convert_w(
    const float* __restrict__ Wq, const float* __restrict__ Wk, const float* __restrict__ W1,
    ushortT* __restrict__ Wth, ushortT* __restrict__ Wtl)
{
    int t = blockIdx.x * 256 + threadIdx.x;        // < 110592
    int w = t / 36864;
    int r = t % 36864;
    int kg = r / 384;                               // 0..95  (8 k's each)
    int n  = r % 384;
    const float* W = (w == 0) ? Wq : (w == 1) ? Wk : W1;
    short8 h, l;
#pragma unroll
    for (int j = 0; j < 8; ++j) {
        float v = W[(size_t)(kg * 8 + j) * HHn + n];
        ushortT hb = f2bf(v);
        h[j] = (short)hb;
        l[j] = (short)f2bf(v - bf2f(hb));
    }
    size_t off = (size_t)w * 294912 + (size_t)n * 768 + kg * 8;
    *reinterpret_cast<short8*>(&Wth[off]) = h;
    *reinterpret_cast<short8*>(&Wtl[off]) = l;
}

// ---------------------------------------------------------------------------
// Kernel 1-new: bf16x3 MFMA projection GEMM.
// z=0: Q = Xhi@Wq_hi (1 term, hi output only, row-major).
// z=1: K = bf16x3(X@Wk)  -> swizzled Kp hi/lo.
// z=2: U = bf16x3(X@W1)  -> swizzled Up hi/lo.
// 128x128 tile, BK=32, 24 K-steps, 256 thr (4 waves in 2x2, each 64x64 = 16 tiles).
// Seg-XOR swizzle folded into the DMA *global* address (LDS image linear ->
// frag ds_read_b128 2-way bank alias = free). Epilogue staged via LDS (stride
// 272B) for 16B coalesced stores into attn's swizzled global layouts.
// ---------------------------------------------------------------------------
__global__ __launch_bounds__(256, 3) void proj_mfma(
    const ushortT* __restrict__ Xhi, const ushortT* __restrict__ Xlo,
    const ushortT* __restrict__ Wth, const ushortT* __restrict__ Wtl,
    const float* __restrict__ bq, const float* __restrict__ bk, const float* __restrict__ b1,
    ushortT* __restrict__ Qhi, ushortT* __restrict__ Khi, ushortT* __restrict__ Klo,
    ushortT* __restrict__ Uhi, ushortT* __restrict__ Ulo)
{
    __shared__ __align__(16) unsigned char smem[34816];
    // staging: Ah @0, Al @8192, Bh @16384, Bl @24576 (each 128 rows x 64B)

    const int wsel = blockIdx.z;
    const bool full = (wsel != 0);
    const float* bias = (wsel == 0) ? bq : (wsel == 1) ? bk : b1;
    const ushortT* Wh = Wth + (size_t)wsel * 294912;
    const ushortT* Wl = Wtl + (size_t)wsel * 294912;
    const int m0 = blockIdx.x * 128;
    const int n0 = blockIdx.y * 128;

    const int tid = threadIdx.x, wid = tid >> 6, lane = tid & 63;
    const int quad = lane >> 4, l15 = lane & 15;
    const int mw = (wid >> 1) * 64, nw = (wid & 1) * 64;
    const int r4 = lane >> 2, s2 = lane & 3;
    const int fs = (l15 >> 1) & 3;                 // frag seg swizzle

    f32x4 acc[4][4];
#pragma unroll
    for (int mt = 0; mt < 4; ++mt)
#pragma unroll
        for (int nt = 0; nt < 4; ++nt) acc[mt][nt] = (f32x4){0.f, 0.f, 0.f, 0.f};

    for (int ks = 0; ks < 24; ++ks) {
        const int k0 = ks * 32;
        __syncthreads();
        {
            const int rb = wid * 32;               // this wave stages rows rb..rb+31
#pragma unroll
            for (int h = 0; h < 2; ++h) {
                int row = rb + h * 16 + r4;
                int sw = (row >> 1) & 3;
                size_t gsegA = (size_t)(m0 + row) * 768 + k0 + ((s2 ^ sw) << 3);
                size_t gsegB = (size_t)(n0 + row) * 768 + k0 + ((s2 ^ sw) << 3);
                gld16(&Xhi[gsegA], smem + (rb + h * 16) * 64);
                gld16(&Wh[gsegB],  smem + 16384 + (rb + h * 16) * 64);
                if (full) {
                    gld16(&Xlo[gsegA], smem + 8192  + (rb + h * 16) * 64);
                    gld16(&Wl[gsegB],  smem + 24576 + (rb + h * 16) * 64);
                }
            }
        }
        __syncthreads();

        short8 ah[4], bh[4], al[4], bl[4];
#pragma unroll
        for (int t = 0; t < 4; ++t) {
            int aaddr = (mw + t * 16 + l15) * 64 + ((quad ^ fs) << 4);
            int baddr = (nw + t * 16 + l15) * 64 + ((quad ^ fs) << 4);
            ah[t] = *reinterpret_cast<const short8*>(smem + aaddr);
            bh[t] = *reinterpret_cast<const short8*>(smem + 16384 + baddr);
            if (full) {
                al[t] = *reinterpret_cast<const short8*>(smem + 8192  + aaddr);
                bl[t] = *reinterpret_cast<const short8*>(smem + 24576 + baddr);
            }
        }
#pragma unroll
        for (int mt = 0; mt < 4; ++mt)
#pragma unroll
            for (int nt = 0; nt < 4; ++nt) {
                acc[mt][nt] = __builtin_amdgcn_mfma_f32_16x16x32_bf16(ah[mt], bh[nt], acc[mt][nt], 0, 0, 0);
                if (full) {
                    acc[mt][nt] = __builtin_amdgcn_mfma_f32_16x16x32_bf16(ah[mt], bl[nt], acc[mt][nt], 0, 0, 0);
                    acc[mt][nt] = __builtin_amdgcn_mfma_f32_16x16x32_bf16(al[mt], bh[nt], acc[mt][nt], 0, 0, 0);
                }
            }
    }
    __syncthreads();

    float bv[4];
#pragma unroll
    for (int nt = 0; nt < 4; ++nt) bv[nt] = bias[n0 + nw + nt * 16 + l15];

    if (wsel == 0) {
        // ---- Q: [m][n] LDS, row-major global, hi only ----
#pragma unroll
        for (int mt = 0; mt < 4; ++mt)
#pragma unroll
            for (int nt = 0; nt < 4; ++nt)
#pragma unroll
                for (int rg = 0; rg < 4; ++rg) {
                    float v = acc[mt][nt][rg] + bv[nt];
                    *reinterpret_cast<ushortT*>(smem + (mw + mt * 16 + quad * 4 + rg) * 272
                                                     + (nw + nt * 16 + l15) * 2) = f2bf(v);
                }
        __syncthreads();
#pragma unroll
        for (int i = 0; i < 8; ++i) {
            int idx = i * 256 + tid, ml = idx >> 4, cl = idx & 15;
            *reinterpret_cast<uint4*>(&Qhi[(size_t)(m0 + ml) * HHn + n0 + cl * 8]) =
                *reinterpret_cast<const uint4*>(smem + ml * 272 + cl * 16);
        }
    } else if (wsel == 1) {
        // ---- K: [m][n] LDS, two passes (hi then lo), swizzled Kp layout ----
#pragma unroll
        for (int pass = 0; pass < 2; ++pass) {
            if (pass) __syncthreads();
#pragma unroll
            for (int mt = 0; mt < 4; ++mt)
#pragma unroll
                for (int nt = 0; nt < 4; ++nt)
#pragma unroll
                    for (int rg = 0; rg < 4; ++rg) {
                        float v = acc[mt][nt][rg] + bv[nt];
                        ushortT hb = f2bf(v);
                        ushortT outw = pass ? f2bf(v - bf2f(hb)) : hb;
                        *reinterpret_cast<ushortT*>(smem + (mw + mt * 16 + quad * 4 + rg) * 272
                                                         + (nw + nt * 16 + l15) * 2) = outw;
                    }
            __syncthreads();
            ushortT* dst = pass ? Klo : Khi;
#pragma unroll
            for (int i = 0; i < 8; ++i) {
                int idx = i * 256 + tid, ml = idx >> 4, cl = idx & 15;
                int m = m0 + ml, bb2 = m >> 11, kg = m & 2047, kt = kg >> 6, key = kg & 63;
                int sc_ = ((n0 >> 3) + cl) ^ (key & 7);
                size_t off = ((size_t)(bb2 * 32 + kt) * 64 + key) * 384 + sc_ * 8;
                *reinterpret_cast<uint4*>(&dst[off]) =
                    *reinterpret_cast<const uint4*>(smem + ml * 272 + cl * 16);
            }
        }
    } else {
        // ---- U: [n][m] LDS (transposed), two passes, swizzled Up layout ----
#pragma unroll
        for (int pass = 0; pass < 2; ++pass) {
            if (pass) __syncthreads();
#pragma unroll
            for (int mt = 0; mt < 4; ++mt)
#pragma unroll
                for (int nt = 0; nt < 4; ++nt) {
                    short4v pk;
#pragma unroll
                    for (int rg = 0; rg < 4; ++rg) {
                        float v = acc[mt][nt][rg] + bv[nt];
                        ushortT hb = f2bf(v);
                        pk[rg] = (short)(pass ? f2bf(v - bf2f(hb)) : hb);
                    }
                    *reinterpret_cast<short4v*>(smem + (nw + nt * 16 + l15) * 272
                                                     + (mw + mt * 16 + quad * 4) * 2) = pk;
                }
            __syncthreads();
            ushortT* dst = pass ? Ulo : Uhi;
#pragma unroll
            for (int i = 0; i < 8; ++i) {
                int idx = i * 256 + tid, dl = idx >> 4, ms = idx & 15;
                int dim = n0 + dl;
                int m = m0 + ms * 8, bb2 = m >> 11, tib = m & 2047;
                int kc = tib >> 5, k8 = (tib >> 3) & 3;
                int sk = k8 ^ (dim & 3);
                size_t off = ((size_t)(bb2 * 64 + kc) * 384 + dim) * 32 + sk * 8;
                *reinterpret_cast<uint4*>(&dst[off]) =
                    *reinterpret_cast<const uint4*>(smem + dl * 272 + ms * 16);
            }
        }
    }
}

// ---------------------------------------------------------------------------
// Kernel 1-fallback: fp32 projection GEMM (round-4 version), used only when
// ws_size is too small for the bf16x3 path's extra arrays.
// ---------------------------------------------------------------------------
__global__ __launch_bounds__(256) void proj_gemm(
    const float* __restrict__ X,
    const float* __restrict__ Wq, const float* __restrict__ bq,
    const float* __restrict__ Wk, const float* __restrict__ bk,
    const float* __restrict__ W1, const float* __restrict__ b1,
    ushortT* __restrict__ Qhi, ushortT* __restrict__ Khi, ushortT* __restrict__ Klo,
    ushortT* __restrict__ Uhi, ushortT* __restrict__ Ulo)
{
    const float* W; const float* bias;
    const int wsel = blockIdx.z;
    if (wsel == 0)      { W = Wq; bias = bq; }
    else if (wsel == 1) { W = Wk; bias = bk; }
    else                { W = W1; bias = b1; }

    const int m0  = blockIdx.x * 128;
    const int n0  = blockIdx.y * 128;
    const int tid = threadIdx.x;
    const int im  = tid >> 4;
    const int jn  = tid & 15;

    __shared__ __align__(16) float sA[16][132];
    __shared__ __align__(16) float sB[16][132];

    float acc[8][8];
#pragma unroll
    for (int i = 0; i < 8; ++i)
#pragma unroll
        for (int j = 0; j < 8; ++j) acc[i][j] = 0.f;

    for (int k0 = 0; k0 < Hn; k0 += 16) {
        __syncthreads();
#pragma unroll
        for (int it = 0; it < 2; ++it) {
            int f = tid + 256 * it;
            int row = f >> 2, k4 = (f & 3) * 4;
            float4 v = *reinterpret_cast<const float4*>(
                &X[(size_t)(m0 + row) * Hn + k0 + k4]);
            sA[k4 + 0][row] = v.x; sA[k4 + 1][row] = v.y;
            sA[k4 + 2][row] = v.z; sA[k4 + 3][row] = v.w;
        }
#pragma unroll
        for (int it = 0; it < 2; ++it) {
            int f = tid + 256 * it;
            int kk = f >> 5, n4 = (f & 31) * 4;
            *reinterpret_cast<float4*>(&sB[kk][n4]) =
                *reinterpret_cast<const float4*>(&W[(size_t)(k0 + kk) * HHn + n0 + n4]);
        }
        __syncthreads();
#pragma unroll
        for (int kk = 0; kk < 16; ++kk) {
            float a[8], bb[8];
            *reinterpret_cast<float4*>(&a[0])  = *reinterpret_cast<const float4*>(&sA[kk][im * 8]);
            *reinterpret_cast<float4*>(&a[4])  = *reinterpret_cast<const float4*>(&sA[kk][im * 8 + 4]);
            *reinterpret_cast<float4*>(&bb[0]) = *reinterpret_cast<const float4*>(&sB[kk][jn * 8]);
            *reinterpret_cast<float4*>(&bb[4]) = *reinterpret_cast<const float4*>(&sB[kk][jn * 8 + 4]);
#pragma unroll
            for (int i = 0; i < 8; ++i)
#pragma unroll
                for (int j = 0; j < 8; ++j) acc[i][j] += a[i] * bb[j];
        }
    }

    if (wsel == 0) {
#pragma unroll
        for (int i = 0; i < 8; ++i) {
            size_t m = (size_t)m0 + im * 8 + i;
            int nb = n0 + jn * 8;
            short8 hv;
#pragma unroll
            for (int j = 0; j < 8; ++j) hv[j] = (short)f2bf(acc[i][j] + bias[nb + j]);
            *reinterpret_cast<short8*>(&Qhi[m * HHn + nb]) = hv;
        }
    } else if (wsel == 1) {
        const int bb = m0 >> 11;
        const int bibase = m0 & 2047;
#pragma unroll
        for (int i = 0; i < 8; ++i) {
            int kg = bibase + im * 8 + i;
            int kt = kg >> 6, key = kg & 63;
            size_t rowoff = ((size_t)(bb * 32 + kt) * 64 + key) * 384;
            int sc_ = ((n0 >> 3) + jn) ^ (key & 7);
            short8 hv, lv;
#pragma unroll
            for (int j = 0; j < 8; ++j) {
                float v = acc[i][j] + bias[n0 + jn * 8 + j];
                ushortT hb = f2bf(v);
                hv[j] = (short)hb;
                lv[j] = (short)f2bf(v - bf2f(hb));
            }
            *reinterpret_cast<short8*>(&Khi[rowoff + sc_ * 8]) = hv;
            *reinterpret_cast<short8*>(&Klo[rowoff + sc_ * 8]) = lv;
        }
    } else {
        const int bb = m0 >> 11;
        const int tib = (m0 & 2047) + im * 8;
        const int kc = tib >> 5, k8 = (tib >> 3) & 3;
        const size_t cbase = (size_t)(bb * 64 + kc) * 384;
#pragma unroll
        for (int j = 0; j < 8; ++j) {
            int dim = n0 + jn * 8 + j;
            int sk = k8 ^ (dim & 3);
            float bvv = bias[dim];
            short8 hv, lv;
#pragma unroll
            for (int i = 0; i < 8; ++i) {
                float v = acc[i][j] + bvv;
                ushortT hb = f2bf(v);
                hv[i] = (short)hb;
                lv[i] = (short)f2bf(v - bf2f(hb));
            }
            size_t off = (cbase + dim) * 32 + sk * 8;
            *reinterpret_cast<short8*>(&Uhi[off]) = hv;
            *reinterpret_cast<short8*>(&Ulo[off]) = lv;
        }
    }
}

// ---------------------------------------------------------------------------
// Kernel 2: bf16 MFMA flash attention (round-4, unchanged).
// ---------------------------------------------------------------------------
__global__ __launch_bounds__(256, 2) void attn_mfma(
    const ushortT* Qg, const ushortT* __restrict__ Kp, const ushortT* __restrict__ Up,
    const int* __restrict__ am, ushortT* Hp)
{
    __shared__ __align__(16) unsigned char smem[81920];
    ushortT* sP = (ushortT*)(smem + 73728);

    const int tid  = threadIdx.x;
    const int wid  = tid >> 6;
    const int lane = tid & 63;
    const int quad = lane >> 4;
    const int l15  = lane & 15;
    const int b    = blockIdx.y;
    const int q0   = blockIdx.x * 64;
    const size_t rowbase = (size_t)b * Sn + q0;
    const int* amb = am + b * Sn;

    const ushortT* Kbase = Kp + (size_t)b * 32 * 64 * 384;
    const ushortT* Ubase = Up + (size_t)b * 64 * 12288;

    const int r0 = wid * 16;
    short8 qf[12];
#pragma unroll
    for (int ks = 0; ks < 12; ++ks)
        qf[ks] = *reinterpret_cast<const short8*>(
            &Qg[(rowbase + r0 + l15) * HHn + ks * 32 + quad * 8]);

    f32x4 o[4][6];
#pragma unroll
    for (int rt = 0; rt < 4; ++rt)
#pragma unroll
        for (int dt = 0; dt < 6; ++dt) o[rt][dt] = (f32x4){0.f, 0.f, 0.f, 0.f};
    float denacc[4] = {0.f, 0.f, 0.f, 0.f};

    int ia = 0, ibx = 24576, ic = 49152;
    stage24k(Kbase, smem + ia, tid);
    stage24k(Kbase + 12288, smem + ibx, tid);
    __syncthreads();

    const int d0 = wid * 96;

    for (int kt = 0; kt < 32; ++kt) {
        stage24k(Ubase + (size_t)(kt * 2) * 12288, smem + ic, tid);

        f32x4 sc[4];
#pragma unroll
        for (int ct = 0; ct < 4; ++ct) sc[ct] = (f32x4){0.f, 0.f, 0.f, 0.f};
#pragma unroll
        for (int ks = 0; ks < 12; ++ks) {
#pragma unroll
            for (int ct = 0; ct < 4; ++ct) {
                int kl = (ct & 1) * 16 + l15;
                const unsigned char* Bk = smem + ((ct < 2) ? ia : ibx);
                short8 bf = *reinterpret_cast<const short8*>(
                    Bk + kl * 768 + ((((ks << 2) + quad) ^ (kl & 7)) << 4));
                sc[ct] = __builtin_amdgcn_mfma_f32_16x16x32_bf16(qf[ks], bf, sc[ct], 0, 0, 0);
            }
        }

        float dp[4] = {0.f, 0.f, 0.f, 0.f};
#pragma unroll
        for (int ct = 0; ct < 4; ++ct) {
            int col = ct * 16 + l15;
            float mval = (amb[kt * 64 + col] != 0) ? 1.f : 0.f;
#pragma unroll
            for (int rg = 0; rg < 4; ++rg) {
                int row = r0 + quad * 4 + rg;
                float p = __expf(sc[ct][rg] * SCALE) * mval;
                sP[row * 64 + (((col >> 3) ^ (row & 7)) << 3) + (col & 7)] = f2bf(p);
                dp[rg] += p;
            }
        }
#pragma unroll
        for (int off = 1; off < 16; off <<= 1)
#pragma unroll
            for (int rg = 0; rg < 4; ++rg) dp[rg] += __shfl_xor(dp[rg], off, 16);
#pragma unroll
        for (int rg = 0; rg < 4; ++rg) denacc[rg] += dp[rg];

        __syncthreads();

        stage24k(Ubase + (size_t)(kt * 2 + 1) * 12288, smem + ia, tid);
        if (kt < 31) stage24k(Kbase + (size_t)(kt + 1) * 24576, smem + ibx, tid);

        {
            const unsigned char* Bu = smem + ic;
            short8 pa[4];
#pragma unroll
            for (int rt = 0; rt < 4; ++rt)
                pa[rt] = *reinterpret_cast<const short8*>(
                    &sP[(16 * rt + l15) * 64 + ((quad ^ (l15 & 7)) << 3)]);
#pragma unroll
            for (int dt = 0; dt < 6; ++dt) {
                short8 u = *reinterpret_cast<const short8*>(
                    Bu + (d0 + 16 * dt + l15) * 64 + ((quad ^ (l15 & 3)) << 4));
#pragma unroll
                for (int rt = 0; rt < 4; ++rt)
                    o[rt][dt] = __builtin_amdgcn_mfma_f32_16x16x32_bf16(pa[rt], u, o[rt][dt], 0, 0, 0);
            }
        }
        __syncthreads();

        if (kt < 31) stage24k(Kbase + (size_t)(kt + 1) * 24576 + 12288, smem + ic, tid);

        {
            const unsigned char* Bu = smem + ia;
            short8 pa[4];
#pragma unroll
            for (int rt = 0; rt < 4; ++rt)
                pa[rt] = *reinterpret_cast<const short8*>(
                    &sP[(16 * rt + l15) * 64 + (((4 + quad) ^ (l15 & 7)) << 3)]);
#pragma unroll
            for (int dt = 0; dt < 6; ++dt) {
                short8 u = *reinterpret_cast<const short8*>(
                    Bu + (d0 + 16 * dt + l15) * 64 + ((quad ^ (l15 & 3)) << 4));
#pragma unroll
                for (int rt = 0; rt < 4; ++rt)
                    o[rt][dt] = __builtin_amdgcn_mfma_f32_16x16x32_bf16(pa[rt], u, o[rt][dt], 0, 0, 0);
            }
        }
        __syncthreads();

        int t = ia; ia = ibx; ibx = ic; ic = t;
    }

    float* sDenF = (float*)smem;
    if (l15 == 0) {
#pragma unroll
        for (int rg = 0; rg < 4; ++rg) sDenF[r0 + quad * 4 + rg] = denacc[rg];
    }
    __syncthreads();
    ushortT* sHp = (ushortT*)(smem + 512);
#pragma unroll
    for (int rt = 0; rt < 4; ++rt)
#pragma unroll
        for (int rg = 0; rg < 4; ++rg) {
            int row = rt * 16 + quad * 4 + rg;
            float inv = 1.f / sDenF[row];
#pragma unroll
            for (int dt = 0; dt < 6; ++dt)
                sHp[row * 384 + d0 + dt * 16 + l15] = f2bf(o[rt][dt][rg] * inv);
        }
    __syncthreads();
#pragma unroll
    for (int i = 0; i < 12; ++i) {
        int idx = i * 256 + tid;
        *reinterpret_cast<uint4*>(&Hp[rowbase * HHn + idx * 8]) =
            *reinterpret_cast<const uint4*>(&sHp[idx * 8]);
    }
}

// ---------------------------------------------------------------------------
// Kernel 3: LN+relu+dot(W2)+mask -> approx token_scores; zero patch counter.
// ---------------------------------------------------------------------------
__global__ __launch_bounds__(256) void ln_score_kernel(
    const ushortT* __restrict__ Hp, const float* __restrict__ g1, const float* __restrict__ be1,
    const float* __restrict__ W2, const float* __restrict__ b2,
    const int* __restrict__ am, float* __restrict__ scores, int* __restrict__ count)
{
    if (blockIdx.x == 0 && threadIdx.x == 0) *count = 0;
    const int row  = blockIdx.x * 4 + (threadIdx.x >> 6);
    const int lane = threadIdx.x & 63;
    const ushortT* x = Hp + (size_t)row * HHn;
    float v[6];
#pragma unroll
    for (int j = 0; j < 6; ++j) v[j] = bf2f(x[lane + 64 * j]);
    float s = 0.f;
#pragma unroll
    for (int j = 0; j < 6; ++j) s += v[j];
#pragma unroll
    for (int off = 32; off > 0; off >>= 1) s += __shfl_xor(s, off, 64);
    const float mean = s * (1.0f / 384.0f);
    float q = 0.f;
#pragma unroll
    for (int j = 0; j < 6; ++j) { float d = v[j] - mean; q += d * d; }
#pragma unroll
    for (int off = 32; off > 0; off >>= 1) q += __shfl_xor(q, off, 64);
    const float rstd = rsqrtf(q * (1.0f / 384.0f) + 1e-5f);
    float part = 0.f;
#pragma unroll
    for (int j = 0; j < 6; ++j) {
        int d = lane + 64 * j;
        float h = (v[j] - mean) * rstd * g1[d] + be1[d];
        h = fmaxf(h, 0.f);
        part += h * W2[d];
    }
#pragma unroll
    for (int off = 32; off > 0; off >>= 1) part += __shfl_xor(part, off, 64);
    if (lane == 0) {
        float scv = part + b2[0];
        if (am[row] == 0) scv = -10000.0f;
        scores[row] = scv;
    }
}

// ---------------------------------------------------------------------------
// Kernel 4: approx span scan; flag tokens of spans within EPS of approx best.
// ---------------------------------------------------------------------------
__global__ __launch_bounds__(256) void span_flag_kernel(
    const float* __restrict__ scores, const int* __restrict__ am,
    int* __restrict__ list, int* __restrict__ count)
{
    __shared__ float cum[Sn + 1];
    __shared__ float psum[257];
    __shared__ float bval[256];
    __shared__ int   sred[256];
    __shared__ int   sInfo[1];
    __shared__ float sBest;
    __shared__ unsigned char sflag[Sn];

    const int b = blockIdx.x, tid = threadIdx.x;
    for (int i = tid; i < Sn; i += 256) sflag[i] = 0;

    int vl = 0;
    for (int i = tid; i < Sn; i += 256) vl += am[b * Sn + i];
    sred[tid] = vl;
    __syncthreads();
    if (tid == 0) { int t = 0; for (int i = 0; i < 256; ++i) t += sred[i]; sInfo[0] = t; }
    __syncthreads();
    const int valid_len = sInfo[0];

    float loc[8]; float tot = 0.f;
#pragma unroll
    for (int k2 = 0; k2 < 8; ++k2) { loc[k2] = scores[b * Sn + tid * 8 + k2]; tot += loc[k2]; }
    psum[tid + 1] = tot;
    __syncthreads();
    if (tid == 0) {
        psum[0] = 0.f;
        float r = 0.f;
        for (int i = 1; i <= 256; ++i) { float t = psum[i]; psum[i] = r + t; r += t; }
    }
    __syncthreads();
    {
        float r = (tid == 0) ? 0.f : psum[tid];
        if (tid == 0) cum[0] = 0.f;
#pragma unroll
        for (int k2 = 0; k2 < 8; ++k2) { r += loc[k2]; cum[tid * 8 + k2 + 1] = r; }
    }
    __syncthreads();

    float bv = -3.0e30f;
    for (int flat = tid; flat < 18 * Sn; flat += 256) {
        int l = flat >> 11, st = flat & (Sn - 1), L = 3 + l, end = st + L;
        float val;
        if (end <= valid_len) {
            int ec = end < Sn ? end : Sn;
            val = (cum[ec] - cum[st]) / (float)L + (0.01f * (float)L) / 20.0f;
        } else val = -1.0e30f;
        if (val > bv) bv = val;
    }
    bval[tid] = bv;
    __syncthreads();
    if (tid == 0) {
        float best = bval[0];
        for (int i = 1; i < 256; ++i) if (bval[i] > best) best = bval[i];
        sBest = best;
    }
    __syncthreads();

    if (valid_len > 3) {
        const float thr = sBest - EPS_PATCH;
        for (int flat = tid; flat < 18 * Sn; flat += 256) {
            int l = flat >> 11, st = flat & (Sn - 1), L = 3 + l, end = st + L;
            if (end <= valid_len) {
                int ec = end < Sn ? end : Sn;
                float val = (cum[ec] - cum[st]) / (float)L + (0.01f * (float)L) / 20.0f;
                if (val >= thr)
                    for (int t = st; t < end; ++t) sflag[t] = 1;
            }
        }
        __syncthreads();
        for (int t = tid; t < Sn; t += 256)
            if (sflag[t]) { int idx = atomicAdd(count, 1); list[idx] = (b << 16) | t; }
    }
}

// ---------------------------------------------------------------------------
// Kernel 5: exact fp32 recompute of flagged tokens' scores.
// ---------------------------------------------------------------------------
static __device__ __forceinline__ float block_sum256(float v, float* sws, int tid)
{
#pragma unroll
    for (int off = 32; off > 0; off >>= 1) v += __shfl_xor(v, off, 64);
    __syncthreads();
    if ((tid & 63) == 0) sws[tid >> 6] = v;
    __syncthreads();
    return sws[0] + sws[1] + sws[2] + sws[3];
}

__global__ __launch_bounds__(256) void patch_kernel(
    const int* __restrict__ list, const int* __restrict__ count,
    const float* __restrict__ X, const float* __restrict__ Wq, const float* __restrict__ bq,
    const ushortT* __restrict__ Khi, const ushortT* __restrict__ Klo,
    const ushortT* __restrict__ Uhi, const ushortT* __restrict__ Ulo,
    const float* __restrict__ g1, const float* __restrict__ be1,
    const float* __restrict__ W2, const float* __restrict__ b2,
    const int* __restrict__ am, float* __restrict__ scores)
{
    __shared__ float sx[Hn];
    __shared__ float sq[HHn];
    __shared__ float sp[Sn];
    __shared__ float sws[4];
    const int tid = threadIdx.x;
    const int n = *count;

    for (int li = blockIdx.x; li < n; li += gridDim.x) {
        int e = list[li];
        int b = e >> 16, t = e & 0xffff;
        __syncthreads();
        for (int d = tid; d < Hn; d += 256) sx[d] = X[((size_t)b * Sn + t) * Hn + d];
        __syncthreads();
        for (int d = tid; d < HHn; d += 256) {
            float a = bq[d];
            for (int k = 0; k < Hn; ++k) a += sx[k] * Wq[(size_t)k * HHn + d];
            sq[d] = a;
        }
        __syncthreads();
        float dpart = 0.f;
        for (int j = tid; j < Sn; j += 256) {
            float p = 0.f;
            if (am[b * Sn + j] != 0) {
                int kt = j >> 6, key = j & 63, kk7 = key & 7;
                size_t ro = ((size_t)(b * 32 + kt) * 64 + key) * 384;
                const ushortT* kh = &Khi[ro];
                const ushortT* kl = &Klo[ro];
                float s = 0.f;
                for (int c = 0; c < 48; ++c) {
                    int dbase = (c ^ kk7) << 3;
                    for (int ee = 0; ee < 8; ++ee)
                        s += sq[dbase + ee] * (bf2f(kh[c * 8 + ee]) + bf2f(kl[c * 8 + ee]));
                }
                p = expf(s * SCALE);
            }
            sp[j] = p; dpart += p;
        }
        const float den = block_sum256(dpart, sws, tid);

        float cown[2] = {0.f, 0.f};
        {
            int ii = 0;
            for (int d = tid; d < HHn; d += 256, ++ii) {
                int d3 = d & 3;
                float c = 0.f;
                for (int kc = 0; kc < 64; ++kc) {
                    size_t ub = ((size_t)(b * 64 + kc) * 384 + d) * 32;
                    const ushortT* uh = &Uhi[ub];
                    const ushortT* ul = &Ulo[ub];
                    for (int k8 = 0; k8 < 4; ++k8) {
                        int sk = k8 ^ d3;
                        int j0 = kc * 32 + k8 * 8;
                        for (int ee = 0; ee < 8; ++ee)
                            c += sp[j0 + ee] * (bf2f(uh[sk * 8 + ee]) + bf2f(ul[sk * 8 + ee]));
                    }
                }
                cown[ii] = c / den;
            }
        }
        float ssum = cown[0] + cown[1];
        const float mean = block_sum256(ssum, sws, tid) * (1.0f / 384.0f);
        float vsum = 0.f;
        {
            int ii = 0;
            for (int d = tid; d < HHn; d += 256, ++ii) {
                float dv = cown[ii] - mean; vsum += dv * dv;
            }
        }
        const float var = block_sum256(vsum, sws, tid) * (1.0f / 384.0f);
        const float rstd = rsqrtf(var + 1e-5f);
        float spart = 0.f;
        {
            int ii = 0;
            for (int d = tid; d < HHn; d += 256, ++ii) {
                float h = (cown[ii] - mean) * rstd * g1[d] + be1[d];
                h = fmaxf(h, 0.f);
                spart += h * W2[d];
            }
        }
        const float sc = block_sum256(spart, sws, tid) + b2[0];
        if (tid == 0)
            scores[b * Sn + t] = (am[b * Sn + t] != 0) ? sc : -10000.0f;
        __syncthreads();
    }
}

// ---------------------------------------------------------------------------
// Kernel 6: final span argmax (patched scores) + pooling.
// ---------------------------------------------------------------------------
__global__ __launch_bounds__(256) void span_pool_kernel(
    const float* __restrict__ scores, const int* __restrict__ am,
    const float* __restrict__ X, float* __restrict__ pooled)
{
    __shared__ float cum[Sn + 1];
    __shared__ float psum[257];
    __shared__ float bval[256];
    __shared__ int   bidx[256];
    __shared__ int   sred[256];
    __shared__ int   sInfo[2];

    const int b = blockIdx.x, tid = threadIdx.x;

    int vl = 0;
    for (int i = tid; i < Sn; i += 256) vl += am[b * Sn + i];
    sred[tid] = vl;
    __syncthreads();
    if (tid == 0) { int t = 0; for (int i = 0; i < 256; ++i) t += sred[i]; sInfo[0] = t; }
    __syncthreads();
    const int valid_len = sInfo[0];

    float loc[8]; float tot = 0.f;
#pragma unroll
    for (int k2 = 0; k2 < 8; ++k2) { loc[k2] = scores[b * Sn + tid * 8 + k2]; tot += loc[k2]; }
    psum[tid + 1] = tot;
    __syncthreads();
    if (tid == 0) {
        psum[0] = 0.f;
        float r = 0.f;
        for (int i = 1; i <= 256; ++i) { float t = psum[i]; psum[i] = r + t; r += t; }
    }
    __syncthreads();
    {
        float r = (tid == 0) ? 0.f : psum[tid];
        if (tid == 0) cum[0] = 0.f;
#pragma unroll
        for (int k2 = 0; k2 < 8; ++k2) { r += loc[k2]; cum[tid * 8 + k2 + 1] = r; }
    }
    __syncthreads();

    float bv = -3.0e30f; int bi = 0x7fffffff;
    for (int flat = tid; flat < 18 * Sn; flat += 256) {
        int l  = flat >> 11;
        int st = flat & (Sn - 1);
        int L  = 3 + l;
        int end = st + L;
        float val;
        if (end <= valid_len) {
            int ec = end < Sn ? end : Sn;
            val = (cum[ec] - cum[st]) / (float)L + (0.01f * (float)L) / 20.0f;
        } else val = -1.0e30f;
        if (val > bv) { bv = val; bi = flat; }
    }
    bval[tid] = bv; bidx[tid] = bi;
    __syncthreads();
    if (tid == 0) {
        float best = bval[0]; int besti = bidx[0];
        for (int i = 1; i < 256; ++i) {
            if (bval[i] > best || (bval[i] == best && bidx[i] < besti)) {
                best = bval[i]; besti = bidx[i];
            }
        }
        int st, len;
        if (valid_len <= 3) { st = 0; len = valid_len; }
        else { int l = besti >> 11; st = besti & (Sn - 1); len = 3 + l; }
        sInfo[0] = st; sInfo[1] = len;
    }
    __syncthreads();
    const int st = sInfo[0], len = sInfo[1];
    for (int d = tid; d < Hn; d += 256) {
        float s2 = 0.f;
        for (int i = 0; i < len; ++i) s2 += X[((size_t)b * Sn + st + i) * Hn + d];
        pooled[b * Hn + d] = s2 / ((float)len + 1e-6f);
    }
}

// ---------------------------------------------------------------------------
// Kernel 7: head.
// ---------------------------------------------------------------------------
__global__ __launch_bounds__(384) void head_kernel(
    const float* __restrict__ pooled,
    const float* __restrict__ Wc1, const float* __restrict__ bc1,
    const float* __restrict__ g2, const float* __restrict__ be2,
    const float* __restrict__ Wc2, const float* __restrict__ bc2,
    const float* __restrict__ Mint,
    const float* __restrict__ Wcls, const float* __restrict__ bcls,
    const float* __restrict__ X, float* __restrict__ out)
{
    __shared__ float sp[768];
    __shared__ float sh[384];
    __shared__ float scs[64];
    __shared__ float scp[64];
    __shared__ float red[6];
    __shared__ float stat;

    const int b = blockIdx.x, tid = threadIdx.x;
    sp[tid]       = pooled[b * Hn + tid];
    sp[tid + 384] = pooled[b * Hn + 384 + tid];
    __syncthreads();

    float z = bc1[tid];
    for (int k2 = 0; k2 < Hn; ++k2) z += sp[k2] * Wc1[(size_t)k2 * HHn + tid];

    float s = z;
#pragma unroll
    for (int off = 32; off > 0; off >>= 1) s += __shfl_xor(s, off, 64);
    if ((tid & 63) == 0) red[tid >> 6] = s;
    __syncthreads();
    if (tid == 0) stat = (red[0] + red[1] + red[2] + red[3] + red[4] + red[5]) * (1.0f / 384.0f);
    __syncthreads();
    const float mean = stat;
    float dv = z - mean;
    float qq = dv * dv;
#pragma unroll
    for (int off = 32; off > 0; off >>= 1) qq += __shfl_xor(qq, off, 64);
    if ((tid & 63) == 0) red[tid >> 6] = qq;
    __syncthreads();
    if (tid == 0) stat = (red[0] + red[1] + red[2] + red[3] + red[4] + red[5]) * (1.0f / 384.0f);
    __syncthreads();
    const float rstd = rsqrtf(stat + 1e-5f);
    float h = fmaxf(dv * rstd * g2[tid] + be2[tid], 0.f);
    sh[tid] = h;
    __syncthreads();
    if (tid < 64) {
        float c = bc2[tid];
        for (int k2 = 0; k2 < HHn; ++k2) c += sh[k2] * Wc2[k2 * 64 + tid];
        scs[tid] = c;
    }
    __syncthreads();
    if (tid < 64) {
        float a2 = scs[tid];
        for (int c2 = 0; c2 < 64; ++c2) {
            float m   = 0.5f * (Mint[c2 * 64 + tid] + Mint[tid * 64 + c2]);
            float sym = 1.0f / (1.0f + expf(-m));
            a2 += scs[c2] * sym;
        }
        scp[tid] = 1.0f / (1.0f + expf(-a2));
    }
    __syncthreads();
    if (tid < 4) {
        float lg = bcls[tid];
        for (int c2 = 0; c2 < 64; ++c2) lg += scp[c2] * Wcls[c2 * 4 + tid];
        const float* cls = X + (size_t)b * Sn * Hn;
        for (int d2 = 0; d2 < Hn; ++d2) lg += cls[d2] * Wcls[(64 + d2) * 4 + tid];
        out[b * 4 + tid] = lg;
    }
}

// ---------------------------------------------------------------------------
extern "C" void kernel_launch(void* const* d_in, const int* in_sizes, int n_in,
                              void* d_out, int out_size, void* d_ws, size_t ws_size,
                              hipStream_t stream)
{
    const float* X    = (const float*)d_in[0];
    const int*   am   = (const int*)  d_in[1];
    const float* Wq   = (const float*)d_in[2];
    const float* bq   = (const float*)d_in[3];
    const float* Wk   = (const float*)d_in[4];
    const float* bk   = (const float*)d_in[5];
    const float* W1   = (const float*)d_in[6];
    const float* b1   = (const float*)d_in[7];
    const float* g1   = (const float*)d_in[8];
    const float* be1  = (const float*)d_in[9];
    const float* W2   = (const float*)d_in[10];
    const float* b2   = (const float*)d_in[11];
    const float* Wc1  = (const float*)d_in[12];
    const float* bc1  = (const float*)d_in[13];
    const float* g2   = (const float*)d_in[14];
    const float* be2  = (const float*)d_in[15];
    const float* Wc2  = (const float*)d_in[16];
    const float* bc2  = (const float*)d_in[17];
    const float* Mint = (const float*)d_in[18];
    const float* Wcls = (const float*)d_in[19];
    const float* bcls = (const float*)d_in[20];

    const size_t NTb = (size_t)Bn * Sn * HHn;   // 12,582,912 elems
    ushortT* Qhi  = (ushortT*)d_ws;
    ushortT* Kp   = Qhi + NTb;
    ushortT* Kplo = Kp  + NTb;
    ushortT* Upp  = Kplo + NTb;
    ushortT* Uplo = Upp + NTb;
    float* scores = (float*)(Uplo + NTb);
    float* pooled = scores + (size_t)Bn * Sn;
    int* list     = (int*)(pooled + (size_t)Bn * Hn);
    int* count    = list + Bn * Sn;
    // new-path extras (placed after the common arrays)
    ushortT* Xhi  = (ushortT*)(count + 4);
    const size_t NX = (size_t)Bn * Sn * Hn;     // 25,165,824
    ushortT* Xlo  = Xhi + NX;
    ushortT* Wth  = Xlo + NX;                   // 3 x 384 x 768
    ushortT* Wtl  = Wth + 3 * 294912;
    const size_t NEED = (size_t)((unsigned char*)(Wtl + 3 * 294912) - (unsigned char*)d_ws);

    ushortT* Hp   = Qhi;   // alias: attn reads Q rows before writing same rows

    if (ws_size >= NEED) {
        convert_x<<<24576, 256, 0, stream>>>(X, Xhi, Xlo);
        convert_w<<<432, 256, 0, stream>>>(Wq, Wk, W1, Wth, Wtl);
        proj_mfma<<<dim3(256, 3, 3), 256, 0, stream>>>(Xhi, Xlo, Wth, Wtl, bq, bk, b1,
                                                       Qhi, Kp, Kplo, Upp, Uplo);
    } else {
        proj_gemm<<<dim3(256, 3, 3), 256, 0, stream>>>(X, Wq, bq, Wk, bk, W1, b1,
                                                       Qhi, Kp, Kplo, Upp, Uplo);
    }
    attn_mfma<<<dim3(Sn / 64, Bn), 256, 0, stream>>>(Qhi, Kp, Upp, am, Hp);
    ln_score_kernel<<<(Bn * Sn) / 4, 256, 0, stream>>>(Hp, g1, be1, W2, b2, am, scores, count);
    span_flag_kernel<<<Bn, 256, 0, stream>>>(scores, am, list, count);
    patch_kernel<<<1024, 256, 0, stream>>>(list, count, X, Wq, bq, Kp, Kplo, Upp, Uplo,
                                           g1, be1, W2, b2, am, scores);
    span_pool_kernel<<<Bn, 256, 0, stream>>>(scores, am, X, pooled);
    head_kernel<<<Bn, 384, 0, stream>>>(pooled, Wc1, bc1, g2, be2, Wc2, bc2,
                                        Mint, Wcls, bcls, X, (float*)d_out);
}